// Round 1
// baseline (4890.475 us; speedup 1.0000x reference)
//
#include <hip/hip_runtime.h>
#include <math.h>

constexpr int N_NODES = 20000;
constexpr int DIM = 512;       // NODE_DIM == HIDDEN
constexpr int N_GRAPHS = 64;

// ---------------- copy (row-major fp32, float4 grid-stride) ----------------
__global__ void copy_rows(const float* __restrict__ src, float* __restrict__ dst, int n_float4) {
  int i = blockIdx.x * blockDim.x + threadIdx.x;
  int stride = gridDim.x * blockDim.x;
  const float4* s = (const float4*)src;
  float4* d = (float4*)dst;
  for (; i < n_float4; i += stride) d[i] = s[i];
}

// ---------------- edge scatter-add: Out[dst[e]] += X[src[e]] ----------------
// 2 edges per 256-thread block; 128 threads/edge, one float4 each (512 dims).
__global__ void scatter_add_edges(const float* __restrict__ X, const int* __restrict__ srcI,
                                  const int* __restrict__ dstI, float* __restrict__ Out,
                                  int n_edges) {
  int e = blockIdx.x * 2 + (threadIdx.x >> 7);
  int t = threadIdx.x & 127;
  if (e >= n_edges) return;
  int s = srcI[e];
  int d = dstI[e];
  float4 v = ((const float4*)(X + (size_t)s * DIM))[t];
  float* o = Out + (size_t)d * DIM + (size_t)t * 4;
  atomicAdd(o + 0, v.x);
  atomicAdd(o + 1, v.y);
  atomicAdd(o + 2, v.z);
  atomicAdd(o + 3, v.w);
}

// ---------------- fp32 GEMM: C[M,N] = A[M,K] @ W[K,N] + bias ----------------
// 64x64 tile / block, 256 threads, 4x4 micro-tile per thread, TK=16.
__global__ __launch_bounds__(256) void gemm_bias(const float* __restrict__ A,
                                                 const float* __restrict__ W,
                                                 const float* __restrict__ bias,
                                                 float* __restrict__ C,
                                                 int M, int N, int K) {
  __shared__ float As[16][65];  // A tile transposed: As[k][m]
  __shared__ float Bs[16][65];  // B tile: Bs[k][n]
  int tid = threadIdx.x;
  int tx = tid & 15;        // output col group
  int ty = tid >> 4;        // output row group
  int bm = blockIdx.x * 64;
  int bn = blockIdx.y * 64;

  int lr = tid >> 2;        // 0..63 : A-tile row
  int lc = (tid & 3) * 4;   // 0,4,8,12 : A-tile k offset
  int br = tid >> 4;        // 0..15 : B-tile k row
  int bc = (tid & 15) * 4;  // 0..60 : B-tile col offset

  float acc[4][4] = {};

  for (int k0 = 0; k0 < K; k0 += 16) {
    int am = bm + lr;
    float4 av = make_float4(0.f, 0.f, 0.f, 0.f);
    if (am < M) av = *(const float4*)(A + (size_t)am * K + k0 + lc);
    As[lc + 0][lr] = av.x;
    As[lc + 1][lr] = av.y;
    As[lc + 2][lr] = av.z;
    As[lc + 3][lr] = av.w;
    float4 bv = *(const float4*)(W + (size_t)(k0 + br) * N + bn + bc);
    Bs[br][bc + 0] = bv.x;
    Bs[br][bc + 1] = bv.y;
    Bs[br][bc + 2] = bv.z;
    Bs[br][bc + 3] = bv.w;
    __syncthreads();
#pragma unroll
    for (int kk = 0; kk < 16; ++kk) {
      float a0 = As[kk][ty * 4 + 0];
      float a1 = As[kk][ty * 4 + 1];
      float a2 = As[kk][ty * 4 + 2];
      float a3 = As[kk][ty * 4 + 3];
      float b0 = Bs[kk][tx * 4 + 0];
      float b1 = Bs[kk][tx * 4 + 1];
      float b2 = Bs[kk][tx * 4 + 2];
      float b3 = Bs[kk][tx * 4 + 3];
      acc[0][0] = fmaf(a0, b0, acc[0][0]); acc[0][1] = fmaf(a0, b1, acc[0][1]);
      acc[0][2] = fmaf(a0, b2, acc[0][2]); acc[0][3] = fmaf(a0, b3, acc[0][3]);
      acc[1][0] = fmaf(a1, b0, acc[1][0]); acc[1][1] = fmaf(a1, b1, acc[1][1]);
      acc[1][2] = fmaf(a1, b2, acc[1][2]); acc[1][3] = fmaf(a1, b3, acc[1][3]);
      acc[2][0] = fmaf(a2, b0, acc[2][0]); acc[2][1] = fmaf(a2, b1, acc[2][1]);
      acc[2][2] = fmaf(a2, b2, acc[2][2]); acc[2][3] = fmaf(a2, b3, acc[2][3]);
      acc[3][0] = fmaf(a3, b0, acc[3][0]); acc[3][1] = fmaf(a3, b1, acc[3][1]);
      acc[3][2] = fmaf(a3, b2, acc[3][2]); acc[3][3] = fmaf(a3, b3, acc[3][3]);
    }
    __syncthreads();
  }

#pragma unroll
  for (int i = 0; i < 4; ++i) {
    int m = bm + ty * 4 + i;
    if (m >= M) continue;
#pragma unroll
    for (int j = 0; j < 4; ++j) {
      int n = bn + tx * 4 + j;
      C[(size_t)m * N + n] = acc[i][j] + bias[n];
    }
  }
}

// ---------------- segment pooling (batch sorted) ----------------
__device__ __forceinline__ int lower_bound_i(const int* __restrict__ a, int n, int v) {
  int lo = 0, hi = n;
  while (lo < hi) {
    int mid = (lo + hi) >> 1;
    if (a[mid] < v) lo = mid + 1; else hi = mid;
  }
  return lo;
}

__global__ void pool_segments(const float* __restrict__ H, const int* __restrict__ batch,
                              float* __restrict__ pooled, int n_nodes) {
  int g = blockIdx.x;                       // graph
  int c = blockIdx.y * 128 + threadIdx.x;   // dim 0..511
  int start = lower_bound_i(batch, n_nodes, g);
  int end   = lower_bound_i(batch, n_nodes, g + 1);
  float acc = 0.f;
  for (int i = start; i < end; ++i) acc += H[(size_t)i * DIM + c];
  pooled[g * DIM + c] = acc;
}

// ---------------- fused classifier head ----------------
// z = relu(pooled @ Wc1 + bc1); out = sigmoid(z @ Wc2 + bc2)
__global__ __launch_bounds__(256) void classifier(const float* __restrict__ pooled,
                                                  const float* __restrict__ Wc1,
                                                  const float* __restrict__ bc1,
                                                  const float* __restrict__ Wc2,
                                                  const float* __restrict__ bc2,
                                                  float* __restrict__ out) {
  int g = blockIdx.x;
  int j = threadIdx.x;  // 0..255 : hidden unit
  __shared__ float p[512];
  p[j] = pooled[g * 512 + j];
  p[j + 256] = pooled[g * 512 + 256 + j];
  __syncthreads();
  float acc = bc1[j];
  for (int k = 0; k < 512; ++k) acc = fmaf(p[k], Wc1[k * 256 + j], acc);
  float z = fmaxf(acc, 0.f);
  float part = z * Wc2[j];
  // wave64 reduce then cross-wave
  for (int off = 32; off > 0; off >>= 1) part += __shfl_down(part, off, 64);
  __shared__ float red[4];
  if ((j & 63) == 0) red[j >> 6] = part;
  __syncthreads();
  if (j == 0) {
    float tot = red[0] + red[1] + red[2] + red[3] + bc2[0];
    out[g] = 1.f / (1.f + expf(-tot));
  }
}

extern "C" void kernel_launch(void* const* d_in, const int* in_sizes, int n_in,
                              void* d_out, int out_size, void* d_ws, size_t ws_size,
                              hipStream_t stream) {
  const float* x    = (const float*)d_in[0];
  const int*   ei   = (const int*)d_in[1];
  const int*   batch= (const int*)d_in[2];
  const float* Wg1  = (const float*)d_in[3];
  const float* bg1  = (const float*)d_in[4];
  const float* Wg2  = (const float*)d_in[5];
  const float* bg2  = (const float*)d_in[6];
  const float* Wc1  = (const float*)d_in[7];
  const float* bc1  = (const float*)d_in[8];
  const float* Wc2  = (const float*)d_in[9];
  const float* bc2  = (const float*)d_in[10];
  float* out = (float*)d_out;

  int n_edges = in_sizes[1] / 2;
  int n_nodes = in_sizes[2];
  const int* srcI = ei;
  const int* dstI = ei + n_edges;

  char* ws = (char*)d_ws;
  size_t rowbytes = (size_t)N_NODES * DIM * sizeof(float);  // 40,960,000 B
  float* bufA   = (float*)ws;                    // t1 / t2
  float* bufB   = (float*)(ws + rowbytes);       // h1 / h2
  float* pooled = (float*)(ws + 2 * rowbytes);   // 64x512

  int n4 = N_NODES * DIM / 4;
  dim3 ggrid((N_NODES + 63) / 64, DIM / 64);

  // Layer 1: t1 = x + scatter(x);  h1 = t1 @ Wg1 + bg1
  copy_rows<<<1024, 256, 0, stream>>>(x, bufA, n4);
  scatter_add_edges<<<(n_edges + 1) / 2, 256, 0, stream>>>(x, srcI, dstI, bufA, n_edges);
  gemm_bias<<<ggrid, 256, 0, stream>>>(bufA, Wg1, bg1, bufB, N_NODES, DIM, DIM);

  // Layer 2: t2 = h1 + scatter(h1); h2 = t2 @ Wg2 + bg2
  copy_rows<<<1024, 256, 0, stream>>>(bufB, bufA, n4);
  scatter_add_edges<<<(n_edges + 1) / 2, 256, 0, stream>>>(bufB, srcI, dstI, bufA, n_edges);
  gemm_bias<<<ggrid, 256, 0, stream>>>(bufA, Wg2, bg2, bufB, N_NODES, DIM, DIM);

  // Pool + head
  pool_segments<<<dim3(N_GRAPHS, 4), 128, 0, stream>>>(bufB, batch, pooled, n_nodes);
  classifier<<<N_GRAPHS, 256, 0, stream>>>(pooled, Wc1, bc1, Wc2, bc2, out);
}

// Round 2
// 874.125 us; speedup vs baseline: 5.5947x; 5.5947x over previous
//
#include <hip/hip_runtime.h>
#include <math.h>

constexpr int N_NODES = 20000;
constexpr int DIM = 512;       // NODE_DIM == HIDDEN
constexpr int N_GRAPHS = 64;
constexpr int SCAN_THREADS = 1024;
constexpr int SCAN_CHUNK = 20;   // 1024*20 = 20480 >= 20000

// ---------------- CSR build ----------------
__global__ void zero_ints(int* __restrict__ p, int n) {
  int i = blockIdx.x * blockDim.x + threadIdx.x;
  int stride = gridDim.x * blockDim.x;
  for (; i < n; i += stride) p[i] = 0;
}

__global__ void count_degrees(const int* __restrict__ dstI, int* __restrict__ counts, int n_edges) {
  int i = blockIdx.x * blockDim.x + threadIdx.x;
  int stride = gridDim.x * blockDim.x;
  for (; i < n_edges; i += stride) atomicAdd(&counts[dstI[i]], 1);
}

// single-block exclusive scan of counts[0..n) -> rowptr[0..n], cursor[i]=rowptr[i]
__global__ __launch_bounds__(SCAN_THREADS) void scan_counts(const int* __restrict__ counts,
                                                            int* __restrict__ rowptr,
                                                            int* __restrict__ cursor, int n) {
  __shared__ int s[SCAN_THREADS];
  int t = threadIdx.x;
  int base = t * SCAN_CHUNK;
  int partial = 0;
#pragma unroll
  for (int j = 0; j < SCAN_CHUNK; ++j) {
    int idx = base + j;
    if (idx < n) partial += counts[idx];
  }
  s[t] = partial;
  __syncthreads();
  // Hillis-Steele inclusive scan
  for (int off = 1; off < SCAN_THREADS; off <<= 1) {
    int v = (t >= off) ? s[t - off] : 0;
    __syncthreads();
    s[t] += v;
    __syncthreads();
  }
  int run = s[t] - partial;  // exclusive prefix for this thread's chunk
#pragma unroll
  for (int j = 0; j < SCAN_CHUNK; ++j) {
    int idx = base + j;
    if (idx < n) {
      rowptr[idx] = run;
      cursor[idx] = run;
      run += counts[idx];
    }
  }
  if (t == SCAN_THREADS - 1) rowptr[n] = s[SCAN_THREADS - 1];
}

__global__ void fill_csr(const int* __restrict__ srcI, const int* __restrict__ dstI,
                         int* __restrict__ cursor, int* __restrict__ esrc, int n_edges) {
  int i = blockIdx.x * blockDim.x + threadIdx.x;
  int stride = gridDim.x * blockDim.x;
  for (; i < n_edges; i += stride) {
    int pos = atomicAdd(&cursor[dstI[i]], 1);
    esrc[pos] = srcI[i];
  }
}

// ---------------- gather aggregation: Out[n] = X[n] + sum_{s in N(n)} X[s] ----------------
// one block (128 threads) per node; thread t owns float4 chunk t (512 dims / 4).
__global__ __launch_bounds__(128) void gather_agg(const float* __restrict__ X,
                                                  const int* __restrict__ rowptr,
                                                  const int* __restrict__ esrc,
                                                  float* __restrict__ Out) {
  int n = blockIdx.x;
  int t = threadIdx.x;
  const float4* Xv = (const float4*)X;
  float4 acc = Xv[(size_t)n * 128 + t];
  int beg = rowptr[n];
  int end = rowptr[n + 1];
  for (int i = beg; i < end; ++i) {
    int s = esrc[i];  // uniform per block -> scalar load
    float4 v = Xv[(size_t)s * 128 + t];
    acc.x += v.x; acc.y += v.y; acc.z += v.z; acc.w += v.w;
  }
  ((float4*)Out)[(size_t)n * 128 + t] = acc;
}

// ---------------- fp32 GEMM: C[M,N] = A[M,K] @ W[K,N] + bias ----------------
__global__ __launch_bounds__(256) void gemm_bias(const float* __restrict__ A,
                                                 const float* __restrict__ W,
                                                 const float* __restrict__ bias,
                                                 float* __restrict__ C,
                                                 int M, int N, int K) {
  __shared__ float As[16][65];  // A tile transposed: As[k][m]
  __shared__ float Bs[16][65];  // B tile: Bs[k][n]
  int tid = threadIdx.x;
  int tx = tid & 15;
  int ty = tid >> 4;
  int bm = blockIdx.x * 64;
  int bn = blockIdx.y * 64;

  int lr = tid >> 2;
  int lc = (tid & 3) * 4;
  int br = tid >> 4;
  int bc = (tid & 15) * 4;

  float acc[4][4] = {};

  for (int k0 = 0; k0 < K; k0 += 16) {
    int am = bm + lr;
    float4 av = make_float4(0.f, 0.f, 0.f, 0.f);
    if (am < M) av = *(const float4*)(A + (size_t)am * K + k0 + lc);
    As[lc + 0][lr] = av.x;
    As[lc + 1][lr] = av.y;
    As[lc + 2][lr] = av.z;
    As[lc + 3][lr] = av.w;
    float4 bv = *(const float4*)(W + (size_t)(k0 + br) * N + bn + bc);
    Bs[br][bc + 0] = bv.x;
    Bs[br][bc + 1] = bv.y;
    Bs[br][bc + 2] = bv.z;
    Bs[br][bc + 3] = bv.w;
    __syncthreads();
#pragma unroll
    for (int kk = 0; kk < 16; ++kk) {
      float a0 = As[kk][ty * 4 + 0];
      float a1 = As[kk][ty * 4 + 1];
      float a2 = As[kk][ty * 4 + 2];
      float a3 = As[kk][ty * 4 + 3];
      float b0 = Bs[kk][tx * 4 + 0];
      float b1 = Bs[kk][tx * 4 + 1];
      float b2 = Bs[kk][tx * 4 + 2];
      float b3 = Bs[kk][tx * 4 + 3];
      acc[0][0] = fmaf(a0, b0, acc[0][0]); acc[0][1] = fmaf(a0, b1, acc[0][1]);
      acc[0][2] = fmaf(a0, b2, acc[0][2]); acc[0][3] = fmaf(a0, b3, acc[0][3]);
      acc[1][0] = fmaf(a1, b0, acc[1][0]); acc[1][1] = fmaf(a1, b1, acc[1][1]);
      acc[1][2] = fmaf(a1, b2, acc[1][2]); acc[1][3] = fmaf(a1, b3, acc[1][3]);
      acc[2][0] = fmaf(a2, b0, acc[2][0]); acc[2][1] = fmaf(a2, b1, acc[2][1]);
      acc[2][2] = fmaf(a2, b2, acc[2][2]); acc[2][3] = fmaf(a2, b3, acc[2][3]);
      acc[3][0] = fmaf(a3, b0, acc[3][0]); acc[3][1] = fmaf(a3, b1, acc[3][1]);
      acc[3][2] = fmaf(a3, b2, acc[3][2]); acc[3][3] = fmaf(a3, b3, acc[3][3]);
    }
    __syncthreads();
  }

#pragma unroll
  for (int i = 0; i < 4; ++i) {
    int m = bm + ty * 4 + i;
    if (m >= M) continue;
#pragma unroll
    for (int j = 0; j < 4; ++j) {
      int n = bn + tx * 4 + j;
      C[(size_t)m * N + n] = acc[i][j] + bias[n];
    }
  }
}

// ---------------- segment pooling (batch sorted) ----------------
__device__ __forceinline__ int lower_bound_i(const int* __restrict__ a, int n, int v) {
  int lo = 0, hi = n;
  while (lo < hi) {
    int mid = (lo + hi) >> 1;
    if (a[mid] < v) lo = mid + 1; else hi = mid;
  }
  return lo;
}

__global__ void pool_segments(const float* __restrict__ H, const int* __restrict__ batch,
                              float* __restrict__ pooled, int n_nodes) {
  int g = blockIdx.x;
  int c = blockIdx.y * 128 + threadIdx.x;
  int start = lower_bound_i(batch, n_nodes, g);
  int end   = lower_bound_i(batch, n_nodes, g + 1);
  float acc = 0.f;
  for (int i = start; i < end; ++i) acc += H[(size_t)i * DIM + c];
  pooled[g * DIM + c] = acc;
}

// ---------------- fused classifier head ----------------
__global__ __launch_bounds__(256) void classifier(const float* __restrict__ pooled,
                                                  const float* __restrict__ Wc1,
                                                  const float* __restrict__ bc1,
                                                  const float* __restrict__ Wc2,
                                                  const float* __restrict__ bc2,
                                                  float* __restrict__ out) {
  int g = blockIdx.x;
  int j = threadIdx.x;
  __shared__ float p[512];
  p[j] = pooled[g * 512 + j];
  p[j + 256] = pooled[g * 512 + 256 + j];
  __syncthreads();
  float acc = bc1[j];
  for (int k = 0; k < 512; ++k) acc = fmaf(p[k], Wc1[k * 256 + j], acc);
  float z = fmaxf(acc, 0.f);
  float part = z * Wc2[j];
  for (int off = 32; off > 0; off >>= 1) part += __shfl_down(part, off, 64);
  __shared__ float red[4];
  if ((j & 63) == 0) red[j >> 6] = part;
  __syncthreads();
  if (j == 0) {
    float tot = red[0] + red[1] + red[2] + red[3] + bc2[0];
    out[g] = 1.f / (1.f + expf(-tot));
  }
}

extern "C" void kernel_launch(void* const* d_in, const int* in_sizes, int n_in,
                              void* d_out, int out_size, void* d_ws, size_t ws_size,
                              hipStream_t stream) {
  const float* x    = (const float*)d_in[0];
  const int*   ei   = (const int*)d_in[1];
  const int*   batch= (const int*)d_in[2];
  const float* Wg1  = (const float*)d_in[3];
  const float* bg1  = (const float*)d_in[4];
  const float* Wg2  = (const float*)d_in[5];
  const float* bg2  = (const float*)d_in[6];
  const float* Wc1  = (const float*)d_in[7];
  const float* bc1  = (const float*)d_in[8];
  const float* Wc2  = (const float*)d_in[9];
  const float* bc2  = (const float*)d_in[10];
  float* out = (float*)d_out;

  int n_edges = in_sizes[1] / 2;
  int n_nodes = in_sizes[2];
  const int* srcI = ei;
  const int* dstI = ei + n_edges;

  char* ws = (char*)d_ws;
  size_t rowbytes = (size_t)N_NODES * DIM * sizeof(float);  // 40,960,000 B
  float* bufA   = (float*)ws;
  float* bufB   = (float*)(ws + rowbytes);
  float* pooled = (float*)(ws + 2 * rowbytes);                        // 64x512
  int*   counts = (int*)(ws + 2 * rowbytes + (1 << 20));              // N
  int*   rowptr = counts + N_NODES;                                   // N+1
  int*   cursor = rowptr + N_NODES + 1;                               // N
  int*   esrc   = cursor + N_NODES;                                   // E

  // --- CSR by destination (rebuilt every launch; same work every call) ---
  zero_ints<<<80, 256, 0, stream>>>(counts, n_nodes);
  count_degrees<<<320, 256, 0, stream>>>(dstI, counts, n_edges);
  scan_counts<<<1, SCAN_THREADS, 0, stream>>>(counts, rowptr, cursor, n_nodes);
  fill_csr<<<320, 256, 0, stream>>>(srcI, dstI, cursor, esrc, n_edges);

  dim3 ggrid((N_NODES + 63) / 64, DIM / 64);

  // Layer 1: t1 = x + agg(x);  h1 = t1 @ Wg1 + bg1
  gather_agg<<<N_NODES, 128, 0, stream>>>(x, rowptr, esrc, bufA);
  gemm_bias<<<ggrid, 256, 0, stream>>>(bufA, Wg1, bg1, bufB, N_NODES, DIM, DIM);

  // Layer 2: t2 = h1 + agg(h1); h2 = t2 @ Wg2 + bg2
  gather_agg<<<N_NODES, 128, 0, stream>>>(bufB, rowptr, esrc, bufA);
  gemm_bias<<<ggrid, 256, 0, stream>>>(bufA, Wg2, bg2, bufB, N_NODES, DIM, DIM);

  // Pool + head
  pool_segments<<<dim3(N_GRAPHS, 4), 128, 0, stream>>>(bufB, batch, pooled, n_nodes);
  classifier<<<N_GRAPHS, 256, 0, stream>>>(pooled, Wc1, bc1, Wc2, bc2, out);
}

// Round 3
// 694.758 us; speedup vs baseline: 7.0391x; 1.2582x over previous
//
#include <hip/hip_runtime.h>
#include <math.h>

constexpr int N_NODES = 20000;
constexpr int DIM = 512;       // NODE_DIM == HIDDEN
constexpr int N_GRAPHS = 64;
constexpr int SCAN_THREADS = 1024;
constexpr int SCAN_CHUNK = 20;   // 1024*20 = 20480 >= 20000

// ---------------- CSR build ----------------
__global__ void zero_ints(int* __restrict__ p, int n) {
  int i = blockIdx.x * blockDim.x + threadIdx.x;
  int stride = gridDim.x * blockDim.x;
  for (; i < n; i += stride) p[i] = 0;
}

__global__ void count_degrees(const int* __restrict__ dstI, int* __restrict__ counts, int n_edges) {
  int i = blockIdx.x * blockDim.x + threadIdx.x;
  int stride = gridDim.x * blockDim.x;
  for (; i < n_edges; i += stride) atomicAdd(&counts[dstI[i]], 1);
}

__global__ __launch_bounds__(SCAN_THREADS) void scan_counts(const int* __restrict__ counts,
                                                            int* __restrict__ rowptr,
                                                            int* __restrict__ cursor, int n) {
  __shared__ int s[SCAN_THREADS];
  int t = threadIdx.x;
  int base = t * SCAN_CHUNK;
  int partial = 0;
#pragma unroll
  for (int j = 0; j < SCAN_CHUNK; ++j) {
    int idx = base + j;
    if (idx < n) partial += counts[idx];
  }
  s[t] = partial;
  __syncthreads();
  for (int off = 1; off < SCAN_THREADS; off <<= 1) {
    int v = (t >= off) ? s[t - off] : 0;
    __syncthreads();
    s[t] += v;
    __syncthreads();
  }
  int run = s[t] - partial;
#pragma unroll
  for (int j = 0; j < SCAN_CHUNK; ++j) {
    int idx = base + j;
    if (idx < n) {
      rowptr[idx] = run;
      cursor[idx] = run;
      run += counts[idx];
    }
  }
  if (t == SCAN_THREADS - 1) rowptr[n] = s[SCAN_THREADS - 1];
}

__global__ void fill_csr(const int* __restrict__ srcI, const int* __restrict__ dstI,
                         int* __restrict__ cursor, int* __restrict__ esrc, int n_edges) {
  int i = blockIdx.x * blockDim.x + threadIdx.x;
  int stride = gridDim.x * blockDim.x;
  for (; i < n_edges; i += stride) {
    int pos = atomicAdd(&cursor[dstI[i]], 1);
    esrc[pos] = srcI[i];
  }
}

// ---------------- gather aggregation: Out[n] = X[n] + sum_{s in N(n)} X[s] ----------------
__global__ __launch_bounds__(128) void gather_agg(const float* __restrict__ X,
                                                  const int* __restrict__ rowptr,
                                                  const int* __restrict__ esrc,
                                                  float* __restrict__ Out) {
  int n = blockIdx.x;
  int t = threadIdx.x;
  const float4* Xv = (const float4*)X;
  float4 acc = Xv[(size_t)n * 128 + t];
  int beg = rowptr[n];
  int end = rowptr[n + 1];
  for (int i = beg; i < end; ++i) {
    int s = esrc[i];
    float4 v = Xv[(size_t)s * 128 + t];
    acc.x += v.x; acc.y += v.y; acc.z += v.z; acc.w += v.w;
  }
  ((float4*)Out)[(size_t)n * 128 + t] = acc;
}

// ---------------- small fp32 GEMM: C[M,N] = A[M,K] @ B[K,N] ----------------
__global__ __launch_bounds__(256) void gemm_nb(const float* __restrict__ A,
                                               const float* __restrict__ W,
                                               float* __restrict__ C,
                                               int M, int N, int K) {
  __shared__ float As[16][65];
  __shared__ float Bs[16][65];
  int tid = threadIdx.x;
  int tx = tid & 15;
  int ty = tid >> 4;
  int bm = blockIdx.x * 64;
  int bn = blockIdx.y * 64;

  int lr = tid >> 2;
  int lc = (tid & 3) * 4;
  int br = tid >> 4;
  int bc = (tid & 15) * 4;

  float acc[4][4] = {};

  for (int k0 = 0; k0 < K; k0 += 16) {
    int am = bm + lr;
    float4 av = make_float4(0.f, 0.f, 0.f, 0.f);
    if (am < M) av = *(const float4*)(A + (size_t)am * K + k0 + lc);
    As[lc + 0][lr] = av.x;
    As[lc + 1][lr] = av.y;
    As[lc + 2][lr] = av.z;
    As[lc + 3][lr] = av.w;
    float4 bv = *(const float4*)(W + (size_t)(k0 + br) * N + bn + bc);
    Bs[br][bc + 0] = bv.x;
    Bs[br][bc + 1] = bv.y;
    Bs[br][bc + 2] = bv.z;
    Bs[br][bc + 3] = bv.w;
    __syncthreads();
#pragma unroll
    for (int kk = 0; kk < 16; ++kk) {
      float a0 = As[kk][ty * 4 + 0];
      float a1 = As[kk][ty * 4 + 1];
      float a2 = As[kk][ty * 4 + 2];
      float a3 = As[kk][ty * 4 + 3];
      float b0 = Bs[kk][tx * 4 + 0];
      float b1 = Bs[kk][tx * 4 + 1];
      float b2 = Bs[kk][tx * 4 + 2];
      float b3 = Bs[kk][tx * 4 + 3];
      acc[0][0] = fmaf(a0, b0, acc[0][0]); acc[0][1] = fmaf(a0, b1, acc[0][1]);
      acc[0][2] = fmaf(a0, b2, acc[0][2]); acc[0][3] = fmaf(a0, b3, acc[0][3]);
      acc[1][0] = fmaf(a1, b0, acc[1][0]); acc[1][1] = fmaf(a1, b1, acc[1][1]);
      acc[1][2] = fmaf(a1, b2, acc[1][2]); acc[1][3] = fmaf(a1, b3, acc[1][3]);
      acc[2][0] = fmaf(a2, b0, acc[2][0]); acc[2][1] = fmaf(a2, b1, acc[2][1]);
      acc[2][2] = fmaf(a2, b2, acc[2][2]); acc[2][3] = fmaf(a2, b3, acc[2][3]);
      acc[3][0] = fmaf(a3, b0, acc[3][0]); acc[3][1] = fmaf(a3, b1, acc[3][1]);
      acc[3][2] = fmaf(a3, b2, acc[3][2]); acc[3][3] = fmaf(a3, b3, acc[3][3]);
    }
    __syncthreads();
  }

#pragma unroll
  for (int i = 0; i < 4; ++i) {
    int m = bm + ty * 4 + i;
    if (m >= M) continue;
#pragma unroll
    for (int j = 0; j < 4; ++j) {
      int n = bn + tx * 4 + j;
      C[(size_t)m * N + n] = acc[i][j];
    }
  }
}

// ---------------- vec-mat: out[n] = sum_k v[k] * M[k][n] ----------------
__global__ void vecmat(const float* __restrict__ v, const float* __restrict__ Mat,
                       float* __restrict__ out, int K, int N) {
  int n = blockIdx.x * blockDim.x + threadIdx.x;
  if (n >= N) return;
  float acc = 0.f;
  for (int k = 0; k < K; ++k) acc = fmaf(v[k], Mat[(size_t)k * N + n], acc);
  out[n] = acc;
}

// ---------------- segment pooling (batch sorted) ----------------
__device__ __forceinline__ int lower_bound_i(const int* __restrict__ a, int n, int v) {
  int lo = 0, hi = n;
  while (lo < hi) {
    int mid = (lo + hi) >> 1;
    if (a[mid] < v) lo = mid + 1; else hi = mid;
  }
  return lo;
}

__global__ void pool_segments(const float* __restrict__ H, const int* __restrict__ batch,
                              float* __restrict__ pooled, int n_nodes) {
  int g = blockIdx.x;
  int c = blockIdx.y * 128 + threadIdx.x;
  int start = lower_bound_i(batch, n_nodes, g);
  int end   = lower_bound_i(batch, n_nodes, g + 1);
  float acc = 0.f;
  for (int i = start; i < end; ++i) acc += H[(size_t)i * DIM + c];
  pooled[g * DIM + c] = acc;
}

// ---------------- per-graph node count n_g and c_g = sum(1+deg_i) ----------------
__global__ __launch_bounds__(256) void graph_counts(const int* __restrict__ batch,
                                                    const int* __restrict__ counts,
                                                    int n_nodes, float* __restrict__ cg,
                                                    float* __restrict__ ng) {
  int g = blockIdx.x;
  int t = threadIdx.x;
  int start = lower_bound_i(batch, n_nodes, g);
  int end   = lower_bound_i(batch, n_nodes, g + 1);
  int sum = 0;
  for (int i = start + t; i < end; i += 256) sum += counts[i];
  __shared__ int s[256];
  s[t] = sum;
  __syncthreads();
  for (int off = 128; off > 0; off >>= 1) {
    if (t < off) s[t] += s[t + off];
    __syncthreads();
  }
  if (t == 0) {
    int n = end - start;
    ng[g] = (float)n;
    cg[g] = (float)(n + s[0]);
  }
}

// ---------------- fused head ----------------
// zpre[j] = sum_k U[g][k]*Wc[k][j] + cg[g]*v1[j] + ng[g]*v2[j] + bc1[j]
// z = relu(zpre); score = z@Wc2 + bc2; out = sigmoid(score)
__global__ __launch_bounds__(256) void head(const float* __restrict__ U,
                                            const float* __restrict__ Wc,
                                            const float* __restrict__ v1,
                                            const float* __restrict__ v2,
                                            const float* __restrict__ cg,
                                            const float* __restrict__ ng,
                                            const float* __restrict__ bc1,
                                            const float* __restrict__ Wc2,
                                            const float* __restrict__ bc2,
                                            float* __restrict__ out) {
  int g = blockIdx.x;
  int j = threadIdx.x;
  __shared__ float p[512];
  p[j] = U[g * 512 + j];
  p[j + 256] = U[g * 512 + 256 + j];
  __syncthreads();
  float acc = bc1[j] + cg[g] * v1[j] + ng[g] * v2[j];
  for (int k = 0; k < 512; ++k) acc = fmaf(p[k], Wc[k * 256 + j], acc);
  float z = fmaxf(acc, 0.f);
  float part = z * Wc2[j];
  for (int off = 32; off > 0; off >>= 1) part += __shfl_down(part, off, 64);
  __shared__ float red[4];
  if ((j & 63) == 0) red[j >> 6] = part;
  __syncthreads();
  if (j == 0) {
    float tot = red[0] + red[1] + red[2] + red[3] + bc2[0];
    out[g] = 1.f / (1.f + expf(-tot));
  }
}

extern "C" void kernel_launch(void* const* d_in, const int* in_sizes, int n_in,
                              void* d_out, int out_size, void* d_ws, size_t ws_size,
                              hipStream_t stream) {
  const float* x    = (const float*)d_in[0];
  const int*   ei   = (const int*)d_in[1];
  const int*   batch= (const int*)d_in[2];
  const float* Wg1  = (const float*)d_in[3];
  const float* bg1  = (const float*)d_in[4];
  const float* Wg2  = (const float*)d_in[5];
  const float* bg2  = (const float*)d_in[6];
  const float* Wc1  = (const float*)d_in[7];
  const float* bc1  = (const float*)d_in[8];
  const float* Wc2  = (const float*)d_in[9];
  const float* bc2  = (const float*)d_in[10];
  float* out = (float*)d_out;

  int n_edges = in_sizes[1] / 2;
  int n_nodes = in_sizes[2];
  const int* srcI = ei;
  const int* dstI = ei + n_edges;

  char* ws = (char*)d_ws;
  size_t off = 0;
  auto alloc = [&](size_t bytes) { char* p = ws + off; off += (bytes + 255) & ~(size_t)255; return p; };
  float* bufA  = (float*)alloc((size_t)N_NODES * DIM * sizeof(float));  // t1
  float* bufB  = (float*)alloc((size_t)N_NODES * DIM * sizeof(float));  // u
  float* U     = (float*)alloc((size_t)N_GRAPHS * DIM * sizeof(float));
  float* T     = (float*)alloc((size_t)DIM * DIM * sizeof(float));      // Wg1@Wg2
  float* Wc    = (float*)alloc((size_t)DIM * 256 * sizeof(float));      // T@Wc1
  float* w1    = (float*)alloc(DIM * sizeof(float));                    // bg1@Wg2
  float* v1    = (float*)alloc(256 * sizeof(float));                    // w1@Wc1
  float* v2    = (float*)alloc(256 * sizeof(float));                    // bg2@Wc1
  float* cg    = (float*)alloc(N_GRAPHS * sizeof(float));
  float* ng    = (float*)alloc(N_GRAPHS * sizeof(float));
  int* counts  = (int*)alloc(N_NODES * sizeof(int));
  int* rowptr  = (int*)alloc((N_NODES + 1) * sizeof(int));
  int* cursor  = (int*)alloc(N_NODES * sizeof(int));
  int* esrc    = (int*)alloc((size_t)n_edges * sizeof(int));

  // --- weight precompute (tiny) ---
  gemm_nb<<<dim3(8, 8), 256, 0, stream>>>(Wg1, Wg2, T, DIM, DIM, DIM);      // T = W1@W2
  gemm_nb<<<dim3(8, 4), 256, 0, stream>>>(T, Wc1, Wc, DIM, 256, DIM);      // Wc = T@Wc1
  vecmat<<<2, 256, 0, stream>>>(bg1, Wg2, w1, DIM, DIM);                   // w1 = b1@W2
  vecmat<<<1, 256, 0, stream>>>(w1, Wc1, v1, DIM, 256);                    // v1 = w1@Wc1
  vecmat<<<1, 256, 0, stream>>>(bg2, Wc1, v2, DIM, 256);                   // v2 = b2@Wc1

  // --- CSR by destination ---
  zero_ints<<<80, 256, 0, stream>>>(counts, n_nodes);
  count_degrees<<<320, 256, 0, stream>>>(dstI, counts, n_edges);
  scan_counts<<<1, SCAN_THREADS, 0, stream>>>(counts, rowptr, cursor, n_nodes);
  fill_csr<<<320, 256, 0, stream>>>(srcI, dstI, cursor, esrc, n_edges);

  // --- graph ops: t1 = x + agg(x); u = t1 + agg(t1); U = seg_sum(u) ---
  gather_agg<<<N_NODES, 128, 0, stream>>>(x, rowptr, esrc, bufA);
  gather_agg<<<N_NODES, 128, 0, stream>>>(bufA, rowptr, esrc, bufB);
  pool_segments<<<dim3(N_GRAPHS, 4), 128, 0, stream>>>(bufB, batch, U, n_nodes);
  graph_counts<<<N_GRAPHS, 256, 0, stream>>>(batch, counts, n_nodes, cg, ng);

  // --- head ---
  head<<<N_GRAPHS, 256, 0, stream>>>(U, Wc, v1, v2, cg, ng, bc1, Wc2, bc2, out);
}

// Round 4
// 578.425 us; speedup vs baseline: 8.4548x; 1.2011x over previous
//
#include <hip/hip_runtime.h>
#include <math.h>

constexpr int N_NODES = 20000;
constexpr int DIM = 512;       // NODE_DIM == HIDDEN
constexpr int N_GRAPHS = 64;
constexpr int SCAN_THREADS = 1024;
constexpr int SCAN_CHUNK = 20;   // 1024*20 = 20480 >= 20000

// ---------------- CSR build ----------------
__global__ void zero_ints(int* __restrict__ p, int n) {
  int i = blockIdx.x * blockDim.x + threadIdx.x;
  int stride = gridDim.x * blockDim.x;
  for (; i < n; i += stride) p[i] = 0;
}

__global__ void count_degrees(const int* __restrict__ dstI, int* __restrict__ counts, int n_edges) {
  int i = blockIdx.x * blockDim.x + threadIdx.x;
  int stride = gridDim.x * blockDim.x;
  for (; i < n_edges; i += stride) atomicAdd(&counts[dstI[i]], 1);
}

__global__ __launch_bounds__(SCAN_THREADS) void scan_counts(const int* __restrict__ counts,
                                                            int* __restrict__ rowptr,
                                                            int* __restrict__ cursor, int n) {
  __shared__ int s[SCAN_THREADS];
  int t = threadIdx.x;
  int base = t * SCAN_CHUNK;
  int partial = 0;
#pragma unroll
  for (int j = 0; j < SCAN_CHUNK; ++j) {
    int idx = base + j;
    if (idx < n) partial += counts[idx];
  }
  s[t] = partial;
  __syncthreads();
  for (int off = 1; off < SCAN_THREADS; off <<= 1) {
    int v = (t >= off) ? s[t - off] : 0;
    __syncthreads();
    s[t] += v;
    __syncthreads();
  }
  int run = s[t] - partial;
#pragma unroll
  for (int j = 0; j < SCAN_CHUNK; ++j) {
    int idx = base + j;
    if (idx < n) {
      rowptr[idx] = run;
      cursor[idx] = run;
      run += counts[idx];
    }
  }
  if (t == SCAN_THREADS - 1) rowptr[n] = s[SCAN_THREADS - 1];
}

__global__ void fill_csr(const int* __restrict__ srcI, const int* __restrict__ dstI,
                         int* __restrict__ cursor, int* __restrict__ esrc, int n_edges) {
  int i = blockIdx.x * blockDim.x + threadIdx.x;
  int stride = gridDim.x * blockDim.x;
  for (; i < n_edges; i += stride) {
    int pos = atomicAdd(&cursor[dstI[i]], 1);
    esrc[pos] = srcI[i];
  }
}

// ---------------- gather aggregation: Out[n] = X[n] + sum_{s in N(n)} X[s] ----------------
__global__ __launch_bounds__(128) void gather_agg(const float* __restrict__ X,
                                                  const int* __restrict__ rowptr,
                                                  const int* __restrict__ esrc,
                                                  float* __restrict__ Out) {
  int n = blockIdx.x;
  int t = threadIdx.x;
  const float4* Xv = (const float4*)X;
  float4 acc = Xv[(size_t)n * 128 + t];
  int beg = rowptr[n];
  int end = rowptr[n + 1];
  for (int i = beg; i < end; ++i) {
    int s = esrc[i];
    float4 v = Xv[(size_t)s * 128 + t];
    acc.x += v.x; acc.y += v.y; acc.z += v.z; acc.w += v.w;
  }
  ((float4*)Out)[(size_t)n * 128 + t] = acc;
}

// ---------------- small fp32 GEMM: C[M,N] = A[M,K] @ B[K,N] ----------------
__global__ __launch_bounds__(256) void gemm_nb(const float* __restrict__ A,
                                               const float* __restrict__ W,
                                               float* __restrict__ C,
                                               int M, int N, int K) {
  __shared__ float As[16][65];
  __shared__ float Bs[16][65];
  int tid = threadIdx.x;
  int tx = tid & 15;
  int ty = tid >> 4;
  int bm = blockIdx.x * 64;
  int bn = blockIdx.y * 64;

  int lr = tid >> 2;
  int lc = (tid & 3) * 4;
  int br = tid >> 4;
  int bc = (tid & 15) * 4;

  float acc[4][4] = {};

  for (int k0 = 0; k0 < K; k0 += 16) {
    int am = bm + lr;
    float4 av = make_float4(0.f, 0.f, 0.f, 0.f);
    if (am < M) av = *(const float4*)(A + (size_t)am * K + k0 + lc);
    As[lc + 0][lr] = av.x;
    As[lc + 1][lr] = av.y;
    As[lc + 2][lr] = av.z;
    As[lc + 3][lr] = av.w;
    float4 bv = *(const float4*)(W + (size_t)(k0 + br) * N + bn + bc);
    Bs[br][bc + 0] = bv.x;
    Bs[br][bc + 1] = bv.y;
    Bs[br][bc + 2] = bv.z;
    Bs[br][bc + 3] = bv.w;
    __syncthreads();
#pragma unroll
    for (int kk = 0; kk < 16; ++kk) {
      float a0 = As[kk][ty * 4 + 0];
      float a1 = As[kk][ty * 4 + 1];
      float a2 = As[kk][ty * 4 + 2];
      float a3 = As[kk][ty * 4 + 3];
      float b0 = Bs[kk][tx * 4 + 0];
      float b1 = Bs[kk][tx * 4 + 1];
      float b2 = Bs[kk][tx * 4 + 2];
      float b3 = Bs[kk][tx * 4 + 3];
      acc[0][0] = fmaf(a0, b0, acc[0][0]); acc[0][1] = fmaf(a0, b1, acc[0][1]);
      acc[0][2] = fmaf(a0, b2, acc[0][2]); acc[0][3] = fmaf(a0, b3, acc[0][3]);
      acc[1][0] = fmaf(a1, b0, acc[1][0]); acc[1][1] = fmaf(a1, b1, acc[1][1]);
      acc[1][2] = fmaf(a1, b2, acc[1][2]); acc[1][3] = fmaf(a1, b3, acc[1][3]);
      acc[2][0] = fmaf(a2, b0, acc[2][0]); acc[2][1] = fmaf(a2, b1, acc[2][1]);
      acc[2][2] = fmaf(a2, b2, acc[2][2]); acc[2][3] = fmaf(a2, b3, acc[2][3]);
      acc[3][0] = fmaf(a3, b0, acc[3][0]); acc[3][1] = fmaf(a3, b1, acc[3][1]);
      acc[3][2] = fmaf(a3, b2, acc[3][2]); acc[3][3] = fmaf(a3, b3, acc[3][3]);
    }
    __syncthreads();
  }

#pragma unroll
  for (int i = 0; i < 4; ++i) {
    int m = bm + ty * 4 + i;
    if (m >= M) continue;
#pragma unroll
    for (int j = 0; j < 4; ++j) {
      int n = bn + tx * 4 + j;
      C[(size_t)m * N + n] = acc[i][j];
    }
  }
}

// ---------------- parallel vec-mat: out[n] = sum_k v[k]*Mat[k][n] ----------------
// block = 256 thr = 4 k-slices x 64 lanes (coalesced over n); grid.x = N/64
__global__ __launch_bounds__(256) void vecmat_fast(const float* __restrict__ v,
                                                   const float* __restrict__ Mat,
                                                   float* __restrict__ out, int K, int N) {
  int lane = threadIdx.x & 63;
  int slice = threadIdx.x >> 6;  // 0..3
  int n = blockIdx.x * 64 + lane;
  float acc = 0.f;
  for (int k = slice; k < K; k += 4)
    acc = fmaf(v[k], Mat[(size_t)k * N + n], acc);
  __shared__ float s[4][64];
  s[slice][lane] = acc;
  __syncthreads();
  if (slice == 0)
    out[n] = s[0][lane] + s[1][lane] + s[2][lane] + s[3][lane];
}

// ---------------- segment pooling (batch sorted) ----------------
__device__ __forceinline__ int lower_bound_i(const int* __restrict__ a, int n, int v) {
  int lo = 0, hi = n;
  while (lo < hi) {
    int mid = (lo + hi) >> 1;
    if (a[mid] < v) lo = mid + 1; else hi = mid;
  }
  return lo;
}

__global__ void pool_segments(const float* __restrict__ H, const int* __restrict__ batch,
                              float* __restrict__ pooled, int n_nodes) {
  int g = blockIdx.x;
  int c = blockIdx.y * 128 + threadIdx.x;
  int start = lower_bound_i(batch, n_nodes, g);
  int end   = lower_bound_i(batch, n_nodes, g + 1);
  float acc = 0.f;
  for (int i = start; i < end; ++i) acc += H[(size_t)i * DIM + c];
  pooled[g * DIM + c] = acc;
}

// ---------------- per-graph node count n_g and c_g = sum(1+deg_i) ----------------
__global__ __launch_bounds__(256) void graph_counts(const int* __restrict__ batch,
                                                    const int* __restrict__ counts,
                                                    int n_nodes, float* __restrict__ cg,
                                                    float* __restrict__ ng) {
  int g = blockIdx.x;
  int t = threadIdx.x;
  int start = lower_bound_i(batch, n_nodes, g);
  int end   = lower_bound_i(batch, n_nodes, g + 1);
  int sum = 0;
  for (int i = start + t; i < end; i += 256) sum += counts[i];
  __shared__ int s[256];
  s[t] = sum;
  __syncthreads();
  for (int off = 128; off > 0; off >>= 1) {
    if (t < off) s[t] += s[t + off];
    __syncthreads();
  }
  if (t == 0) {
    int n = end - start;
    ng[g] = (float)n;
    cg[g] = (float)(n + s[0]);
  }
}

// ---------------- fused head ----------------
__global__ __launch_bounds__(256) void head(const float* __restrict__ U,
                                            const float* __restrict__ Wc,
                                            const float* __restrict__ v1,
                                            const float* __restrict__ v2,
                                            const float* __restrict__ cg,
                                            const float* __restrict__ ng,
                                            const float* __restrict__ bc1,
                                            const float* __restrict__ Wc2,
                                            const float* __restrict__ bc2,
                                            float* __restrict__ out) {
  int g = blockIdx.x;
  int j = threadIdx.x;
  __shared__ float p[512];
  p[j] = U[g * 512 + j];
  p[j + 256] = U[g * 512 + 256 + j];
  __syncthreads();
  float acc = bc1[j] + cg[g] * v1[j] + ng[g] * v2[j];
  for (int k = 0; k < 512; ++k) acc = fmaf(p[k], Wc[k * 256 + j], acc);
  float z = fmaxf(acc, 0.f);
  float part = z * Wc2[j];
  for (int off = 32; off > 0; off >>= 1) part += __shfl_down(part, off, 64);
  __shared__ float red[4];
  if ((j & 63) == 0) red[j >> 6] = part;
  __syncthreads();
  if (j == 0) {
    float tot = red[0] + red[1] + red[2] + red[3] + bc2[0];
    out[g] = 1.f / (1.f + expf(-tot));
  }
}

extern "C" void kernel_launch(void* const* d_in, const int* in_sizes, int n_in,
                              void* d_out, int out_size, void* d_ws, size_t ws_size,
                              hipStream_t stream) {
  const float* x    = (const float*)d_in[0];
  const int*   ei   = (const int*)d_in[1];
  const int*   batch= (const int*)d_in[2];
  const float* Wg1  = (const float*)d_in[3];
  const float* bg1  = (const float*)d_in[4];
  const float* Wg2  = (const float*)d_in[5];
  const float* bg2  = (const float*)d_in[6];
  const float* Wc1  = (const float*)d_in[7];
  const float* bc1  = (const float*)d_in[8];
  const float* Wc2  = (const float*)d_in[9];
  const float* bc2  = (const float*)d_in[10];
  float* out = (float*)d_out;

  int n_edges = in_sizes[1] / 2;
  int n_nodes = in_sizes[2];
  const int* srcI = ei;
  const int* dstI = ei + n_edges;

  char* ws = (char*)d_ws;
  size_t off = 0;
  auto alloc = [&](size_t bytes) { char* p = ws + off; off += (bytes + 255) & ~(size_t)255; return p; };
  float* bufA  = (float*)alloc((size_t)N_NODES * DIM * sizeof(float));  // t1
  float* bufB  = (float*)alloc((size_t)N_NODES * DIM * sizeof(float));  // u
  float* U     = (float*)alloc((size_t)N_GRAPHS * DIM * sizeof(float));
  float* WC    = (float*)alloc((size_t)DIM * 256 * sizeof(float));      // Wg2@Wc1
  float* Wc    = (float*)alloc((size_t)DIM * 256 * sizeof(float));      // Wg1@WC
  float* v1    = (float*)alloc(256 * sizeof(float));                    // bg1@WC
  float* v2    = (float*)alloc(256 * sizeof(float));                    // bg2@Wc1
  float* cg    = (float*)alloc(N_GRAPHS * sizeof(float));
  float* ng    = (float*)alloc(N_GRAPHS * sizeof(float));
  int* counts  = (int*)alloc(N_NODES * sizeof(int));
  int* rowptr  = (int*)alloc((N_NODES + 1) * sizeof(int));
  int* cursor  = (int*)alloc(N_NODES * sizeof(int));
  int* esrc    = (int*)alloc((size_t)n_edges * sizeof(int));

  // --- CSR by destination (big parallel work first) ---
  zero_ints<<<80, 256, 0, stream>>>(counts, n_nodes);
  count_degrees<<<320, 256, 0, stream>>>(dstI, counts, n_edges);
  scan_counts<<<1, SCAN_THREADS, 0, stream>>>(counts, rowptr, cursor, n_nodes);
  fill_csr<<<320, 256, 0, stream>>>(srcI, dstI, cursor, esrc, n_edges);

  // --- graph ops: t1 = x + agg(x); u = t1 + agg(t1); U = seg_sum(u) ---
  gather_agg<<<N_NODES, 128, 0, stream>>>(x, rowptr, esrc, bufA);
  gather_agg<<<N_NODES, 128, 0, stream>>>(bufA, rowptr, esrc, bufB);
  pool_segments<<<dim3(N_GRAPHS, 4), 128, 0, stream>>>(bufB, batch, U, n_nodes);
  graph_counts<<<N_GRAPHS, 256, 0, stream>>>(batch, counts, n_nodes, cg, ng);

  // --- weight precompute: WC = Wg2@Wc1; Wc = Wg1@WC; v1 = bg1@WC; v2 = bg2@Wc1 ---
  gemm_nb<<<dim3(8, 4), 256, 0, stream>>>(Wg2, Wc1, WC, DIM, 256, DIM);
  gemm_nb<<<dim3(8, 4), 256, 0, stream>>>(Wg1, WC, Wc, DIM, 256, DIM);
  vecmat_fast<<<4, 256, 0, stream>>>(bg1, WC, v1, DIM, 256);
  vecmat_fast<<<4, 256, 0, stream>>>(bg2, Wc1, v2, DIM, 256);

  // --- head ---
  head<<<N_GRAPHS, 256, 0, stream>>>(U, Wc, v1, v2, cg, ng, bc1, Wc2, bc2, out);
}

// Round 5
// 514.144 us; speedup vs baseline: 9.5119x; 1.1250x over previous
//
#include <hip/hip_runtime.h>
#include <math.h>

constexpr int N_NODES = 20000;
constexpr int DIM = 512;       // NODE_DIM == HIDDEN
constexpr int NG = 64;
constexpr int KCH = 500;       // U-GEMM k-chunk
constexpr int NCHUNK = 40;     // 40*500 = 20000
constexpr int SCAN_THREADS = 1024;
constexpr int SCAN_CHUNK = 20; // 1024*20 = 20480 >= 20000

// ---------------- misc ----------------
__device__ __forceinline__ int lower_bound_i(const int* __restrict__ a, int n, int v) {
  int lo = 0, hi = n;
  while (lo < hi) {
    int mid = (lo + hi) >> 1;
    if (a[mid] < v) lo = mid + 1; else hi = mid;
  }
  return lo;
}

__global__ void zero_ints(int* __restrict__ p, int n) {
  int i = blockIdx.x * blockDim.x + threadIdx.x;
  int stride = gridDim.x * blockDim.x;
  for (; i < n; i += stride) p[i] = 0;
}

// ng[g] = #nodes in graph g (batch sorted); eh[g] = 0 (edge-hist accumulator)
__global__ void ng_init(const int* __restrict__ batch, int n_nodes,
                        float* __restrict__ ng, float* __restrict__ eh) {
  int g = threadIdx.x;  // 0..63
  int start = lower_bound_i(batch, n_nodes, g);
  int end   = lower_bound_i(batch, n_nodes, g + 1);
  ng[g] = (float)(end - start);
  eh[g] = 0.f;
}

// wT[j][g] = [batch[j]==g]  (one wave per node; also serves as zero-init)
__global__ __launch_bounds__(256) void build_w(const int* __restrict__ batch,
                                               float* __restrict__ wT, int n_nodes) {
  int node = blockIdx.x * 4 + (threadIdx.x >> 6);
  int g = threadIdx.x & 63;
  if (node >= n_nodes) return;
  int b = batch[node];
  wT[(size_t)node * 64 + g] = (g == b) ? 1.f : 0.f;
}

// wT[src[e]][batch[dst[e]]] += 1 ; eh[batch[dst[e]]] += 1 (LDS hist)
__global__ __launch_bounds__(256) void add_edges_w(const int* __restrict__ srcI,
                                                   const int* __restrict__ dstI,
                                                   const int* __restrict__ batch,
                                                   float* __restrict__ wT,
                                                   float* __restrict__ eh, int n_edges) {
  __shared__ int hist[64];
  int t = threadIdx.x;
  if (t < 64) hist[t] = 0;
  __syncthreads();
  int i = blockIdx.x * blockDim.x + t;
  int stride = gridDim.x * blockDim.x;
  for (; i < n_edges; i += stride) {
    int s = srcI[i];
    int b = batch[dstI[i]];
    atomicAdd(&wT[(size_t)s * 64 + b], 1.f);
    atomicAdd(&hist[b], 1);
  }
  __syncthreads();
  if (t < 64 && hist[t] != 0) atomicAdd(&eh[t], (float)hist[t]);
}

// ---------------- CSR by source ----------------
__global__ void count_src(const int* __restrict__ srcI, int* __restrict__ counts, int n_edges) {
  int i = blockIdx.x * blockDim.x + threadIdx.x;
  int stride = gridDim.x * blockDim.x;
  for (; i < n_edges; i += stride) atomicAdd(&counts[srcI[i]], 1);
}

__global__ __launch_bounds__(SCAN_THREADS) void scan_counts(const int* __restrict__ counts,
                                                            int* __restrict__ rowptr,
                                                            int* __restrict__ cursor, int n) {
  __shared__ int s[SCAN_THREADS];
  int t = threadIdx.x;
  int base = t * SCAN_CHUNK;
  int partial = 0;
#pragma unroll
  for (int j = 0; j < SCAN_CHUNK; ++j) {
    int idx = base + j;
    if (idx < n) partial += counts[idx];
  }
  s[t] = partial;
  __syncthreads();
  for (int off = 1; off < SCAN_THREADS; off <<= 1) {
    int v = (t >= off) ? s[t - off] : 0;
    __syncthreads();
    s[t] += v;
    __syncthreads();
  }
  int run = s[t] - partial;
#pragma unroll
  for (int j = 0; j < SCAN_CHUNK; ++j) {
    int idx = base + j;
    if (idx < n) {
      rowptr[idx] = run;
      cursor[idx] = run;
      run += counts[idx];
    }
  }
  if (t == SCAN_THREADS - 1) rowptr[n] = s[SCAN_THREADS - 1];
}

__global__ void fill_csr(const int* __restrict__ srcI, const int* __restrict__ dstI,
                         int* __restrict__ cursor, int* __restrict__ edst, int n_edges) {
  int i = blockIdx.x * blockDim.x + threadIdx.x;
  int stride = gridDim.x * blockDim.x;
  for (; i < n_edges; i += stride) {
    int pos = atomicAdd(&cursor[srcI[i]], 1);
    edst[pos] = dstI[i];
  }
}

// ---------------- cT[k][g] = wT[k][g] + sum_{e:src=k} wT[dst(e)][g] ----------------
__global__ __launch_bounds__(256) void compute_cT(const float* __restrict__ wT,
                                                  const int* __restrict__ rowptr,
                                                  const int* __restrict__ edst,
                                                  float* __restrict__ cT, int n_nodes) {
  int node = blockIdx.x * 4 + (threadIdx.x >> 6);
  int g = threadIdx.x & 63;
  if (node >= n_nodes) return;
  float acc = wT[(size_t)node * 64 + g];
  int beg = rowptr[node];
  int end = rowptr[node + 1];
  for (int i = beg; i < end; ++i) {
    int d = edst[i];
    acc += wT[(size_t)d * 64 + g];
  }
  cT[(size_t)node * 64 + g] = acc;
}

// ---------------- U-GEMM: Upart[chunk][g][n] = sum_{k in chunk} cT[k][g]*x[k][n] ----------------
// grid (8 n-tiles, NCHUNK), block 256 = 4 g-slices x 64 lanes
__global__ __launch_bounds__(256) void ugemm(const float* __restrict__ x,
                                             const float* __restrict__ cT,
                                             float* __restrict__ Upart) {
  int lane = threadIdx.x & 63;
  int slice = threadIdx.x >> 6;  // 0..3 -> graphs [16*slice, 16*slice+16)
  int n = blockIdx.x * 64 + lane;
  int k0 = blockIdx.y * KCH;
  const float4* cT4 = (const float4*)cT;
  float acc[16] = {};
  for (int k = k0; k < k0 + KCH; ++k) {
    float xv = x[(size_t)k * DIM + n];
    float4 c0 = cT4[k * 16 + slice * 4 + 0];
    float4 c1 = cT4[k * 16 + slice * 4 + 1];
    float4 c2 = cT4[k * 16 + slice * 4 + 2];
    float4 c3 = cT4[k * 16 + slice * 4 + 3];
    acc[0]  = fmaf(c0.x, xv, acc[0]);  acc[1]  = fmaf(c0.y, xv, acc[1]);
    acc[2]  = fmaf(c0.z, xv, acc[2]);  acc[3]  = fmaf(c0.w, xv, acc[3]);
    acc[4]  = fmaf(c1.x, xv, acc[4]);  acc[5]  = fmaf(c1.y, xv, acc[5]);
    acc[6]  = fmaf(c1.z, xv, acc[6]);  acc[7]  = fmaf(c1.w, xv, acc[7]);
    acc[8]  = fmaf(c2.x, xv, acc[8]);  acc[9]  = fmaf(c2.y, xv, acc[9]);
    acc[10] = fmaf(c2.z, xv, acc[10]); acc[11] = fmaf(c2.w, xv, acc[11]);
    acc[12] = fmaf(c3.x, xv, acc[12]); acc[13] = fmaf(c3.y, xv, acc[13]);
    acc[14] = fmaf(c3.z, xv, acc[14]); acc[15] = fmaf(c3.w, xv, acc[15]);
  }
#pragma unroll
  for (int j = 0; j < 16; ++j) {
    int g = slice * 16 + j;
    Upart[((size_t)blockIdx.y * 64 + g) * DIM + n] = acc[j];
  }
}

// ---------------- 32x64-tile fp32 GEMM: C[M,N] = A[M,K] @ B[K,N] ----------------
// block 256, BM=32 BN=64 BK=16; per-thread 2x4 micro-tile. M%32==0,N%64==0,K%16==0.
__global__ __launch_bounds__(256) void gemm32x64(const float* __restrict__ A,
                                                 const float* __restrict__ B,
                                                 float* __restrict__ C,
                                                 int M, int N, int K) {
  __shared__ float As[16][33];
  __shared__ float Bs[16][65];
  int tid = threadIdx.x;
  int tx = tid & 15;   // n-group of 4
  int ty = tid >> 4;   // m-group of 2 (0..15)
  int bm = blockIdx.x * 32;
  int bn = blockIdx.y * 64;

  int ar = tid >> 3;        // 0..31 : A row
  int ac = (tid & 7) * 2;   // 0..14 : A k offset (float2)
  int br = tid >> 4;        // 0..15 : B k row
  int bc = (tid & 15) * 4;  // B col offset (float4)

  float acc[2][4] = {};

  for (int k0 = 0; k0 < K; k0 += 16) {
    float2 av = *(const float2*)(A + (size_t)(bm + ar) * K + k0 + ac);
    As[ac + 0][ar] = av.x;
    As[ac + 1][ar] = av.y;
    float4 bv = *(const float4*)(B + (size_t)(k0 + br) * N + bn + bc);
    Bs[br][bc + 0] = bv.x;
    Bs[br][bc + 1] = bv.y;
    Bs[br][bc + 2] = bv.z;
    Bs[br][bc + 3] = bv.w;
    __syncthreads();
#pragma unroll
    for (int kk = 0; kk < 16; ++kk) {
      float a0 = As[kk][ty * 2 + 0];
      float a1 = As[kk][ty * 2 + 1];
      float b0 = Bs[kk][tx * 4 + 0];
      float b1 = Bs[kk][tx * 4 + 1];
      float b2 = Bs[kk][tx * 4 + 2];
      float b3 = Bs[kk][tx * 4 + 3];
      acc[0][0] = fmaf(a0, b0, acc[0][0]); acc[0][1] = fmaf(a0, b1, acc[0][1]);
      acc[0][2] = fmaf(a0, b2, acc[0][2]); acc[0][3] = fmaf(a0, b3, acc[0][3]);
      acc[1][0] = fmaf(a1, b0, acc[1][0]); acc[1][1] = fmaf(a1, b1, acc[1][1]);
      acc[1][2] = fmaf(a1, b2, acc[1][2]); acc[1][3] = fmaf(a1, b3, acc[1][3]);
    }
    __syncthreads();
  }

#pragma unroll
  for (int i = 0; i < 2; ++i) {
    int m = bm + ty * 2 + i;
#pragma unroll
    for (int j = 0; j < 4; ++j) {
      C[(size_t)m * N + bn + tx * 4 + j] = acc[i][j];
    }
  }
}

// ---------------- parallel vec-mat: out[n] = sum_k v[k]*Mat[k][n] ----------------
__global__ __launch_bounds__(256) void vecmat_fast(const float* __restrict__ v,
                                                   const float* __restrict__ Mat,
                                                   float* __restrict__ out, int K, int N) {
  int lane = threadIdx.x & 63;
  int slice = threadIdx.x >> 6;
  int n = blockIdx.x * 64 + lane;
  float acc = 0.f;
  for (int k = slice; k < K; k += 4)
    acc = fmaf(v[k], Mat[(size_t)k * N + n], acc);
  __shared__ float s[4][64];
  s[slice][lane] = acc;
  __syncthreads();
  if (slice == 0)
    out[n] = s[0][lane] + s[1][lane] + s[2][lane] + s[3][lane];
}

// ---------------- fused head (reduces Upart inline) ----------------
// p = sum_c Upart[c][g][:]; zpre[j] = p@Wc[:,j] + cg*v1[j] + ng*v2[j] + bc1[j]
// z = relu; out[g] = sigmoid(z@Wc2 + bc2)
__global__ __launch_bounds__(256) void head(const float* __restrict__ Upart,
                                            const float* __restrict__ Wc,
                                            const float* __restrict__ v1,
                                            const float* __restrict__ v2,
                                            const float* __restrict__ ng,
                                            const float* __restrict__ eh,
                                            const float* __restrict__ bc1,
                                            const float* __restrict__ Wc2,
                                            const float* __restrict__ bc2,
                                            float* __restrict__ out) {
  int g = blockIdx.x;
  int j = threadIdx.x;
  __shared__ float p[512];
  float s0 = 0.f, s1 = 0.f;
  for (int c = 0; c < NCHUNK; ++c) {
    s0 += Upart[((size_t)c * 64 + g) * DIM + j];
    s1 += Upart[((size_t)c * 64 + g) * DIM + 256 + j];
  }
  p[j] = s0;
  p[j + 256] = s1;
  __syncthreads();
  float cg = ng[g] + eh[g];
  float acc = bc1[j] + cg * v1[j] + ng[g] * v2[j];
  for (int k = 0; k < 512; ++k) acc = fmaf(p[k], Wc[k * 256 + j], acc);
  float z = fmaxf(acc, 0.f);
  float part = z * Wc2[j];
  for (int off = 32; off > 0; off >>= 1) part += __shfl_down(part, off, 64);
  __shared__ float red[4];
  if ((j & 63) == 0) red[j >> 6] = part;
  __syncthreads();
  if (j == 0) {
    float tot = red[0] + red[1] + red[2] + red[3] + bc2[0];
    out[g] = 1.f / (1.f + expf(-tot));
  }
}

extern "C" void kernel_launch(void* const* d_in, const int* in_sizes, int n_in,
                              void* d_out, int out_size, void* d_ws, size_t ws_size,
                              hipStream_t stream) {
  const float* x    = (const float*)d_in[0];
  const int*   ei   = (const int*)d_in[1];
  const int*   batch= (const int*)d_in[2];
  const float* Wg1  = (const float*)d_in[3];
  const float* bg1  = (const float*)d_in[4];
  const float* Wg2  = (const float*)d_in[5];
  const float* bg2  = (const float*)d_in[6];
  const float* Wc1  = (const float*)d_in[7];
  const float* bc1  = (const float*)d_in[8];
  const float* Wc2  = (const float*)d_in[9];
  const float* bc2  = (const float*)d_in[10];
  float* out = (float*)d_out;

  int n_edges = in_sizes[1] / 2;
  int n_nodes = in_sizes[2];
  const int* srcI = ei;
  const int* dstI = ei + n_edges;

  char* ws = (char*)d_ws;
  size_t off = 0;
  auto alloc = [&](size_t bytes) { char* p = ws + off; off += (bytes + 255) & ~(size_t)255; return p; };
  float* wT    = (float*)alloc((size_t)N_NODES * 64 * sizeof(float));       // 5.12 MB
  float* cT    = (float*)alloc((size_t)N_NODES * 64 * sizeof(float));       // 5.12 MB
  float* Upart = (float*)alloc((size_t)NCHUNK * 64 * DIM * sizeof(float));  // 5.24 MB
  float* WC    = (float*)alloc((size_t)DIM * 256 * sizeof(float));          // Wg2@Wc1
  float* Wc    = (float*)alloc((size_t)DIM * 256 * sizeof(float));          // Wg1@WC
  float* v1    = (float*)alloc(256 * sizeof(float));                        // bg1@WC
  float* v2    = (float*)alloc(256 * sizeof(float));                        // bg2@Wc1
  float* ng    = (float*)alloc(NG * sizeof(float));
  float* eh    = (float*)alloc(NG * sizeof(float));
  int* counts  = (int*)alloc(N_NODES * sizeof(int));
  int* rowptr  = (int*)alloc((N_NODES + 1) * sizeof(int));
  int* cursor  = (int*)alloc(N_NODES * sizeof(int));
  int* edst    = (int*)alloc((size_t)n_edges * sizeof(int));

  // --- coefficient build ---
  ng_init<<<1, 64, 0, stream>>>(batch, n_nodes, ng, eh);
  build_w<<<(n_nodes + 3) / 4, 256, 0, stream>>>(batch, wT, n_nodes);
  zero_ints<<<80, 256, 0, stream>>>(counts, n_nodes);
  add_edges_w<<<320, 256, 0, stream>>>(srcI, dstI, batch, wT, eh, n_edges);

  // --- CSR by source ---
  count_src<<<320, 256, 0, stream>>>(srcI, counts, n_edges);
  scan_counts<<<1, SCAN_THREADS, 0, stream>>>(counts, rowptr, cursor, n_nodes);
  fill_csr<<<320, 256, 0, stream>>>(srcI, dstI, cursor, edst, n_edges);

  // --- c coefficients + U = cT^T @ x ---
  compute_cT<<<(n_nodes + 3) / 4, 256, 0, stream>>>(wT, rowptr, edst, cT, n_nodes);
  ugemm<<<dim3(DIM / 64, NCHUNK), 256, 0, stream>>>(x, cT, Upart);

  // --- weight precompute: WC = Wg2@Wc1; Wc = Wg1@WC; v1 = bg1@WC; v2 = bg2@Wc1 ---
  gemm32x64<<<dim3(16, 4), 256, 0, stream>>>(Wg2, Wc1, WC, DIM, 256, DIM);
  gemm32x64<<<dim3(16, 4), 256, 0, stream>>>(Wg1, WC, Wc, DIM, 256, DIM);
  vecmat_fast<<<4, 256, 0, stream>>>(bg1, WC, v1, DIM, 256);
  vecmat_fast<<<4, 256, 0, stream>>>(bg2, Wc1, v2, DIM, 256);

  // --- head ---
  head<<<NG, 256, 0, stream>>>(Upart, Wc, v1, v2, ng, eh, bc1, Wc2, bc2, out);
}

// Round 6
// 392.130 us; speedup vs baseline: 12.4716x; 1.3112x over previous
//
#include <hip/hip_runtime.h>
#include <math.h>

constexpr int N_NODES = 20000;
constexpr int DIM = 512;       // NODE_DIM == HIDDEN
constexpr int NG = 64;
constexpr int KCH = 64;        // U-GEMM k-chunk
constexpr int NCHUNK = (N_NODES + KCH - 1) / KCH;  // 313
constexpr int RSPLIT = 4;
constexpr int CPS = (NCHUNK + RSPLIT - 1) / RSPLIT; // 79
constexpr int SCAN_THREADS = 1024;
constexpr int SCAN_CHUNK = 20; // 1024*20 = 20480 >= 20000

// ---------------- misc ----------------
__device__ __forceinline__ int lower_bound_i(const int* __restrict__ a, int n, int v) {
  int lo = 0, hi = n;
  while (lo < hi) {
    int mid = (lo + hi) >> 1;
    if (a[mid] < v) lo = mid + 1; else hi = mid;
  }
  return lo;
}

// wT[j][g] = [batch[j]==g]; counts[j] = 0; ng/eh init (block 0)
__global__ __launch_bounds__(256) void node_init(const int* __restrict__ batch,
                                                 float* __restrict__ wT,
                                                 int* __restrict__ counts,
                                                 float* __restrict__ ng,
                                                 float* __restrict__ eh, int n_nodes) {
  int node = blockIdx.x * 4 + (threadIdx.x >> 6);
  int g = threadIdx.x & 63;
  if (node < n_nodes) {
    int b = batch[node];
    wT[(size_t)node * 64 + g] = (g == b) ? 1.f : 0.f;
    if (g == 0) counts[node] = 0;
  }
  if (blockIdx.x == 0 && threadIdx.x < 64) {
    int gg = threadIdx.x;
    int s0 = lower_bound_i(batch, n_nodes, gg);
    int e0 = lower_bound_i(batch, n_nodes, gg + 1);
    ng[gg] = (float)(e0 - s0);
    eh[gg] = 0.f;
  }
}

// one pass over edges: wT[src][batch[dst]] += 1; counts[src] += 1; eh hist
__global__ __launch_bounds__(256) void edge_pass(const int* __restrict__ srcI,
                                                 const int* __restrict__ dstI,
                                                 const int* __restrict__ batch,
                                                 float* __restrict__ wT,
                                                 int* __restrict__ counts,
                                                 float* __restrict__ eh, int n_edges) {
  __shared__ int hist[64];
  int t = threadIdx.x;
  if (t < 64) hist[t] = 0;
  __syncthreads();
  int i = blockIdx.x * 256 + t;
  int stride = gridDim.x * 256;
  for (; i < n_edges; i += stride) {
    int s = srcI[i];
    int b = batch[dstI[i]];
    atomicAdd(&wT[(size_t)s * 64 + b], 1.f);
    atomicAdd(&counts[s], 1);
    atomicAdd(&hist[b], 1);
  }
  __syncthreads();
  if (t < 64 && hist[t] != 0) atomicAdd(&eh[t], (float)hist[t]);
}

// ---------------- CSR by source ----------------
__global__ __launch_bounds__(SCAN_THREADS) void scan_counts(const int* __restrict__ counts,
                                                            int* __restrict__ rowptr,
                                                            int* __restrict__ cursor, int n) {
  __shared__ int s[SCAN_THREADS];
  int t = threadIdx.x;
  int base = t * SCAN_CHUNK;
  int partial = 0;
#pragma unroll
  for (int j = 0; j < SCAN_CHUNK; ++j) {
    int idx = base + j;
    if (idx < n) partial += counts[idx];
  }
  s[t] = partial;
  __syncthreads();
  for (int off = 1; off < SCAN_THREADS; off <<= 1) {
    int v = (t >= off) ? s[t - off] : 0;
    __syncthreads();
    s[t] += v;
    __syncthreads();
  }
  int run = s[t] - partial;
#pragma unroll
  for (int j = 0; j < SCAN_CHUNK; ++j) {
    int idx = base + j;
    if (idx < n) {
      rowptr[idx] = run;
      cursor[idx] = run;
      run += counts[idx];
    }
  }
  if (t == SCAN_THREADS - 1) rowptr[n] = s[SCAN_THREADS - 1];
}

__global__ void fill_csr(const int* __restrict__ srcI, const int* __restrict__ dstI,
                         int* __restrict__ cursor, int* __restrict__ edst, int n_edges) {
  int i = blockIdx.x * blockDim.x + threadIdx.x;
  int stride = gridDim.x * blockDim.x;
  for (; i < n_edges; i += stride) {
    int pos = atomicAdd(&cursor[srcI[i]], 1);
    edst[pos] = dstI[i];
  }
}

// ---------------- cT[k][g] = wT[k][g] + sum_{e:src=k} wT[dst(e)][g] ----------------
__global__ __launch_bounds__(256) void compute_cT(const float* __restrict__ wT,
                                                  const int* __restrict__ rowptr,
                                                  const int* __restrict__ edst,
                                                  float* __restrict__ cT, int n_nodes) {
  int node = blockIdx.x * 4 + (threadIdx.x >> 6);
  int g = threadIdx.x & 63;
  if (node >= n_nodes) return;
  float acc = wT[(size_t)node * 64 + g];
  int beg = rowptr[node];
  int end = rowptr[node + 1];
  for (int i = beg; i < end; ++i) {
    int d = edst[i];
    acc += wT[(size_t)d * 64 + g];
  }
  cT[(size_t)node * 64 + g] = acc;
}

// ---------------- U-GEMM: Upart[c][g][n] = sum_{k in chunk c} cT[k][g]*x[k][n] ----------------
// grid (2 n-tiles, NCHUNK), block 256 = 4 g-slices x 64 lanes; cT chunk staged in LDS.
__global__ __launch_bounds__(256) void ugemm(const float* __restrict__ x,
                                             const float* __restrict__ cT,
                                             float* __restrict__ Upart) {
  __shared__ float sc[KCH][64];  // 16 KB
  int t = threadIdx.x;
  int k0 = blockIdx.y * KCH;
  int kmax = (N_NODES - k0) < KCH ? (N_NODES - k0) : KCH;
  // stage cT[k0..k0+kmax][64] -> LDS (float4 coalesced), zero-pad tail
  {
    const float4* src = (const float4*)(cT + (size_t)k0 * 64);
    float4* dst = (float4*)(&sc[0][0]);
    int limit4 = kmax * 16;
    for (int i = t; i < KCH * 16; i += 256) {
      float4 v = make_float4(0.f, 0.f, 0.f, 0.f);
      if (i < limit4) v = src[i];
      dst[i] = v;
    }
  }
  __syncthreads();
  int lane = t & 63;
  int slice = t >> 6;                 // g-range [slice*16, slice*16+16)
  int n4 = blockIdx.x * 64 + lane;    // float4 col index 0..127
  const float4* x4 = (const float4*)x;
  float4 acc[16];
#pragma unroll
  for (int j = 0; j < 16; ++j) acc[j] = make_float4(0.f, 0.f, 0.f, 0.f);
  for (int kk = 0; kk < kmax; ++kk) {
    float4 xv = x4[(size_t)(k0 + kk) * 128 + n4];
#pragma unroll
    for (int j = 0; j < 16; ++j) {
      float c = sc[kk][slice * 16 + j];
      acc[j].x = fmaf(c, xv.x, acc[j].x);
      acc[j].y = fmaf(c, xv.y, acc[j].y);
      acc[j].z = fmaf(c, xv.z, acc[j].z);
      acc[j].w = fmaf(c, xv.w, acc[j].w);
    }
  }
  float4* up = (float4*)Upart;
#pragma unroll
  for (int j = 0; j < 16; ++j) {
    int g = slice * 16 + j;
    up[((size_t)blockIdx.y * 64 + g) * 128 + n4] = acc[j];
  }
}

// ---------------- Upart reduce: Ured[s][g][n] = sum_{c in split s} Upart[c][g][n] ----------------
__global__ __launch_bounds__(128) void reduce_U(const float* __restrict__ Upart,
                                                float* __restrict__ Ured) {
  int g = blockIdx.x;   // 0..63
  int s = blockIdx.y;   // 0..RSPLIT-1
  int t = threadIdx.x;  // 0..127 float4 over 512
  int c0 = s * CPS;
  int c1 = (c0 + CPS < NCHUNK) ? c0 + CPS : NCHUNK;
  const float4* up = (const float4*)Upart;
  float4 acc = make_float4(0.f, 0.f, 0.f, 0.f);
  for (int c = c0; c < c1; ++c) {
    float4 v = up[((size_t)c * 64 + g) * 128 + t];
    acc.x += v.x; acc.y += v.y; acc.z += v.z; acc.w += v.w;
  }
  ((float4*)Ured)[((size_t)s * 64 + g) * 128 + t] = acc;
}

// ---------------- 32x64-tile fp32 GEMM: C[M,N] = A[M,K] @ B[K,N] ----------------
__global__ __launch_bounds__(256) void gemm32x64(const float* __restrict__ A,
                                                 const float* __restrict__ B,
                                                 float* __restrict__ C,
                                                 int M, int N, int K) {
  __shared__ float As[16][33];
  __shared__ float Bs[16][65];
  int tid = threadIdx.x;
  int tx = tid & 15;
  int ty = tid >> 4;
  int bm = blockIdx.x * 32;
  int bn = blockIdx.y * 64;

  int ar = tid >> 3;
  int ac = (tid & 7) * 2;
  int br = tid >> 4;
  int bc = (tid & 15) * 4;

  float acc[2][4] = {};

  for (int k0 = 0; k0 < K; k0 += 16) {
    float2 av = *(const float2*)(A + (size_t)(bm + ar) * K + k0 + ac);
    As[ac + 0][ar] = av.x;
    As[ac + 1][ar] = av.y;
    float4 bv = *(const float4*)(B + (size_t)(k0 + br) * N + bn + bc);
    Bs[br][bc + 0] = bv.x;
    Bs[br][bc + 1] = bv.y;
    Bs[br][bc + 2] = bv.z;
    Bs[br][bc + 3] = bv.w;
    __syncthreads();
#pragma unroll
    for (int kk = 0; kk < 16; ++kk) {
      float a0 = As[kk][ty * 2 + 0];
      float a1 = As[kk][ty * 2 + 1];
      float b0 = Bs[kk][tx * 4 + 0];
      float b1 = Bs[kk][tx * 4 + 1];
      float b2 = Bs[kk][tx * 4 + 2];
      float b3 = Bs[kk][tx * 4 + 3];
      acc[0][0] = fmaf(a0, b0, acc[0][0]); acc[0][1] = fmaf(a0, b1, acc[0][1]);
      acc[0][2] = fmaf(a0, b2, acc[0][2]); acc[0][3] = fmaf(a0, b3, acc[0][3]);
      acc[1][0] = fmaf(a1, b0, acc[1][0]); acc[1][1] = fmaf(a1, b1, acc[1][1]);
      acc[1][2] = fmaf(a1, b2, acc[1][2]); acc[1][3] = fmaf(a1, b3, acc[1][3]);
    }
    __syncthreads();
  }

#pragma unroll
  for (int i = 0; i < 2; ++i) {
    int m = bm + ty * 2 + i;
#pragma unroll
    for (int j = 0; j < 4; ++j) {
      C[(size_t)m * N + bn + tx * 4 + j] = acc[i][j];
    }
  }
}

// ---------------- parallel vec-mat: out[n] = sum_k v[k]*Mat[k][n] ----------------
__global__ __launch_bounds__(256) void vecmat_fast(const float* __restrict__ v,
                                                   const float* __restrict__ Mat,
                                                   float* __restrict__ out, int K, int N) {
  int lane = threadIdx.x & 63;
  int slice = threadIdx.x >> 6;
  int n = blockIdx.x * 64 + lane;
  float acc = 0.f;
  for (int k = slice; k < K; k += 4)
    acc = fmaf(v[k], Mat[(size_t)k * N + n], acc);
  __shared__ float s[4][64];
  s[slice][lane] = acc;
  __syncthreads();
  if (slice == 0)
    out[n] = s[0][lane] + s[1][lane] + s[2][lane] + s[3][lane];
}

// ---------------- fused head ----------------
__global__ __launch_bounds__(256) void head(const float* __restrict__ Ured,
                                            const float* __restrict__ Wc,
                                            const float* __restrict__ v1,
                                            const float* __restrict__ v2,
                                            const float* __restrict__ ng,
                                            const float* __restrict__ eh,
                                            const float* __restrict__ bc1,
                                            const float* __restrict__ Wc2,
                                            const float* __restrict__ bc2,
                                            float* __restrict__ out) {
  int g = blockIdx.x;
  int j = threadIdx.x;
  __shared__ float p[512];
  float s0 = 0.f, s1 = 0.f;
#pragma unroll
  for (int s = 0; s < RSPLIT; ++s) {
    s0 += Ured[((size_t)s * 64 + g) * DIM + j];
    s1 += Ured[((size_t)s * 64 + g) * DIM + 256 + j];
  }
  p[j] = s0;
  p[j + 256] = s1;
  __syncthreads();
  float cg = ng[g] + eh[g];
  float acc = bc1[j] + cg * v1[j] + ng[g] * v2[j];
  for (int k = 0; k < 512; ++k) acc = fmaf(p[k], Wc[k * 256 + j], acc);
  float z = fmaxf(acc, 0.f);
  float part = z * Wc2[j];
  for (int off = 32; off > 0; off >>= 1) part += __shfl_down(part, off, 64);
  __shared__ float red[4];
  if ((j & 63) == 0) red[j >> 6] = part;
  __syncthreads();
  if (j == 0) {
    float tot = red[0] + red[1] + red[2] + red[3] + bc2[0];
    out[g] = 1.f / (1.f + expf(-tot));
  }
}

extern "C" void kernel_launch(void* const* d_in, const int* in_sizes, int n_in,
                              void* d_out, int out_size, void* d_ws, size_t ws_size,
                              hipStream_t stream) {
  const float* x    = (const float*)d_in[0];
  const int*   ei   = (const int*)d_in[1];
  const int*   batch= (const int*)d_in[2];
  const float* Wg1  = (const float*)d_in[3];
  const float* bg1  = (const float*)d_in[4];
  const float* Wg2  = (const float*)d_in[5];
  const float* bg2  = (const float*)d_in[6];
  const float* Wc1  = (const float*)d_in[7];
  const float* bc1  = (const float*)d_in[8];
  const float* Wc2  = (const float*)d_in[9];
  const float* bc2  = (const float*)d_in[10];
  float* out = (float*)d_out;

  int n_edges = in_sizes[1] / 2;
  int n_nodes = in_sizes[2];
  const int* srcI = ei;
  const int* dstI = ei + n_edges;

  char* ws = (char*)d_ws;
  size_t off = 0;
  auto alloc = [&](size_t bytes) { char* p = ws + off; off += (bytes + 255) & ~(size_t)255; return p; };
  float* wT    = (float*)alloc((size_t)N_NODES * 64 * sizeof(float));        // 5.12 MB
  float* cT    = (float*)alloc((size_t)N_NODES * 64 * sizeof(float));        // 5.12 MB
  float* Upart = (float*)alloc((size_t)NCHUNK * 64 * DIM * sizeof(float));   // 41 MB
  float* Ured  = (float*)alloc((size_t)RSPLIT * 64 * DIM * sizeof(float));   // 512 KB
  float* WC    = (float*)alloc((size_t)DIM * 256 * sizeof(float));           // Wg2@Wc1
  float* Wc    = (float*)alloc((size_t)DIM * 256 * sizeof(float));           // Wg1@WC
  float* v1    = (float*)alloc(256 * sizeof(float));                         // bg1@WC
  float* v2    = (float*)alloc(256 * sizeof(float));                         // bg2@Wc1
  float* ng    = (float*)alloc(NG * sizeof(float));
  float* eh    = (float*)alloc(NG * sizeof(float));
  int* counts  = (int*)alloc(N_NODES * sizeof(int));
  int* rowptr  = (int*)alloc((N_NODES + 1) * sizeof(int));
  int* cursor  = (int*)alloc(N_NODES * sizeof(int));
  int* edst    = (int*)alloc((size_t)n_edges * sizeof(int));

  // --- coefficient build: node pass + single edge pass ---
  node_init<<<(n_nodes + 3) / 4, 256, 0, stream>>>(batch, wT, counts, ng, eh, n_nodes);
  edge_pass<<<320, 256, 0, stream>>>(srcI, dstI, batch, wT, counts, eh, n_edges);

  // --- CSR by source ---
  scan_counts<<<1, SCAN_THREADS, 0, stream>>>(counts, rowptr, cursor, n_nodes);
  fill_csr<<<320, 256, 0, stream>>>(srcI, dstI, cursor, edst, n_edges);

  // --- c coefficients + U = cT^T @ x (chunked) + reduce ---
  compute_cT<<<(n_nodes + 3) / 4, 256, 0, stream>>>(wT, rowptr, edst, cT, n_nodes);
  ugemm<<<dim3(2, NCHUNK), 256, 0, stream>>>(x, cT, Upart);
  reduce_U<<<dim3(64, RSPLIT), 128, 0, stream>>>(Upart, Ured);

  // --- weight precompute: WC = Wg2@Wc1; Wc = Wg1@WC; v1 = bg1@WC; v2 = bg2@Wc1 ---
  gemm32x64<<<dim3(16, 4), 256, 0, stream>>>(Wg2, Wc1, WC, DIM, 256, DIM);
  gemm32x64<<<dim3(16, 4), 256, 0, stream>>>(Wg1, WC, Wc, DIM, 256, DIM);
  vecmat_fast<<<4, 256, 0, stream>>>(bg1, WC, v1, DIM, 256);
  vecmat_fast<<<4, 256, 0, stream>>>(bg2, Wc1, v2, DIM, 256);

  // --- head ---
  head<<<NG, 256, 0, stream>>>(Ured, Wc, v1, v2, ng, eh, bc1, Wc2, bc2, out);
}

// Round 7
// 350.141 us; speedup vs baseline: 13.9672x; 1.1199x over previous
//
#include <hip/hip_runtime.h>
#include <math.h>

constexpr int N_NODES = 20000;
constexpr int DIM = 512;       // NODE_DIM == HIDDEN
constexpr int NG = 64;
constexpr int KCH = 128;       // U-GEMM k-chunk
constexpr int NCHUNK = (N_NODES + KCH - 1) / KCH;  // 157 (last chunk kmax=32, %4==0)
constexpr int SCAN_THREADS = 1024;
constexpr int SCAN_CHUNK = 20; // 1024*20 = 20480 >= 20000

// ---------------- misc ----------------
__device__ __forceinline__ int lower_bound_i(const int* __restrict__ a, int n, int v) {
  int lo = 0, hi = n;
  while (lo < hi) {
    int mid = (lo + hi) >> 1;
    if (a[mid] < v) lo = mid + 1; else hi = mid;
  }
  return lo;
}

// wT[j][g] = [batch[j]==g]; ng/eh init (block 0)
__global__ __launch_bounds__(256) void node_init(const int* __restrict__ batch,
                                                 float* __restrict__ wT,
                                                 float* __restrict__ ng,
                                                 float* __restrict__ eh, int n_nodes) {
  int node = blockIdx.x * 4 + (threadIdx.x >> 6);
  int g = threadIdx.x & 63;
  if (node < n_nodes) {
    int b = batch[node];
    wT[(size_t)node * 64 + g] = (g == b) ? 1.f : 0.f;
  }
  if (blockIdx.x == 0 && threadIdx.x < 64) {
    int gg = threadIdx.x;
    int s0 = lower_bound_i(batch, n_nodes, gg);
    int e0 = lower_bound_i(batch, n_nodes, gg + 1);
    ng[gg] = (float)(e0 - s0);
    eh[gg] = 0.f;
  }
}

// edge pass: wT[src][batch[dst]] += 1; eh hist (LDS)
__global__ __launch_bounds__(256) void edge_pass(const int* __restrict__ srcI,
                                                 const int* __restrict__ dstI,
                                                 const int* __restrict__ batch,
                                                 float* __restrict__ wT,
                                                 float* __restrict__ eh, int n_edges) {
  __shared__ int hist[64];
  int t = threadIdx.x;
  if (t < 64) hist[t] = 0;
  __syncthreads();
  int i = blockIdx.x * 256 + t;
  int stride = gridDim.x * 256;
  for (; i < n_edges; i += stride) {
    int s = srcI[i];
    int b = batch[dstI[i]];
    atomicAdd(&wT[(size_t)s * 64 + b], 1.f);
    atomicAdd(&hist[b], 1);
  }
  __syncthreads();
  if (t < 64 && hist[t] != 0) atomicAdd(&eh[t], (float)hist[t]);
}

// counts[j] = out-degree(j) = rowsum(wT[j]) - 1  (wave per node, shfl reduce)
__global__ __launch_bounds__(256) void rowsum_counts(const float* __restrict__ wT,
                                                     int* __restrict__ counts, int n_nodes) {
  int node = blockIdx.x * 4 + (threadIdx.x >> 6);
  int lane = threadIdx.x & 63;
  if (node >= n_nodes) return;
  float v = wT[(size_t)node * 64 + lane];
  for (int off = 32; off > 0; off >>= 1) v += __shfl_down(v, off, 64);
  if (lane == 0) counts[node] = (int)(v + 0.5f) - 1;
}

// ---------------- CSR scan (shfl-based) ----------------
__global__ __launch_bounds__(SCAN_THREADS) void scan_counts(const int* __restrict__ counts,
                                                            int* __restrict__ rowptr,
                                                            int* __restrict__ cursor, int n) {
  int t = threadIdx.x;
  int lane = t & 63;
  int wave = t >> 6;  // 0..15
  int base = t * SCAN_CHUNK;
  int partial = 0;
#pragma unroll
  for (int j = 0; j < SCAN_CHUNK; ++j) {
    int idx = base + j;
    if (idx < n) partial += counts[idx];
  }
  // wave-inclusive scan
  int incl = partial;
  for (int off = 1; off < 64; off <<= 1) {
    int v = __shfl_up(incl, off, 64);
    if (lane >= off) incl += v;
  }
  __shared__ int wsum[16];
  if (lane == 63) wsum[wave] = incl;
  __syncthreads();
  if (wave == 0 && lane < 16) {
    int v = wsum[lane];
    int wincl = v;
    for (int off = 1; off < 16; off <<= 1) {
      int u = __shfl_up(wincl, off, 64);
      if (lane >= off) wincl += u;
    }
    wsum[lane] = wincl - v;  // exclusive wave offset
  }
  __syncthreads();
  int run = incl - partial + wsum[wave];  // exclusive prefix for this thread
#pragma unroll
  for (int j = 0; j < SCAN_CHUNK; ++j) {
    int idx = base + j;
    if (idx < n) {
      rowptr[idx] = run;
      cursor[idx] = run;
      run += counts[idx];
    }
  }
  if (t == SCAN_THREADS - 1) rowptr[n] = run;
}

__global__ void fill_csr(const int* __restrict__ srcI, const int* __restrict__ dstI,
                         int* __restrict__ cursor, int* __restrict__ edst, int n_edges) {
  int i = blockIdx.x * blockDim.x + threadIdx.x;
  int stride = gridDim.x * blockDim.x;
  for (; i < n_edges; i += stride) {
    int pos = atomicAdd(&cursor[srcI[i]], 1);
    edst[pos] = dstI[i];
  }
}

// ---------------- cT[k][g] = wT[k][g] + sum_{e:src=k} wT[dst(e)][g] ----------------
__global__ __launch_bounds__(256) void compute_cT(const float* __restrict__ wT,
                                                  const int* __restrict__ rowptr,
                                                  const int* __restrict__ edst,
                                                  float* __restrict__ cT, int n_nodes) {
  int node = blockIdx.x * 4 + (threadIdx.x >> 6);
  int g = threadIdx.x & 63;
  if (node >= n_nodes) return;
  float acc = wT[(size_t)node * 64 + g];
  int beg = rowptr[node];
  int end = rowptr[node + 1];
  for (int i = beg; i < end; ++i) {
    int d = edst[i];
    acc += wT[(size_t)d * 64 + g];
  }
  cT[(size_t)node * 64 + g] = acc;
}

// ---------------- U-GEMM: Upart[c][g][n] = sum_{k in chunk c} cT[k][g]*x[k][n] ----------------
// grid (4 n-tiles, NCHUNK); block 256 = 4 g-slices x 64 lanes; float2 per lane; k unrolled x4.
__global__ __launch_bounds__(256) void ugemm(const float* __restrict__ x,
                                             const float* __restrict__ cT,
                                             float* __restrict__ Upart) {
  __shared__ float sc[KCH][64];  // 32 KB
  int t = threadIdx.x;
  int k0 = blockIdx.y * KCH;
  int kmax = (N_NODES - k0) < KCH ? (N_NODES - k0) : KCH;  // 128 or 32; %4==0
  {
    const float4* src = (const float4*)(cT + (size_t)k0 * 64);
    float4* dst = (float4*)(&sc[0][0]);
    int limit4 = kmax * 16;
    for (int i = t; i < limit4; i += 256) dst[i] = src[i];
  }
  __syncthreads();
  int lane = t & 63;
  int slice = t >> 6;                 // g-range [slice*16, slice*16+16)
  int n2 = blockIdx.x * 64 + lane;    // float2 col 0..255
  const float2* x2 = (const float2*)x;
  float2 acc[16];
#pragma unroll
  for (int j = 0; j < 16; ++j) acc[j] = make_float2(0.f, 0.f);
  for (int kk = 0; kk < kmax; kk += 4) {
    float2 xv[4];
#pragma unroll
    for (int u = 0; u < 4; ++u)
      xv[u] = x2[(size_t)(k0 + kk + u) * 256 + n2];
#pragma unroll
    for (int u = 0; u < 4; ++u) {
      const float4* cp = (const float4*)&sc[kk + u][slice * 16];
      float4 c0 = cp[0], c1 = cp[1], c2 = cp[2], c3 = cp[3];
      float2 xu = xv[u];
      acc[0].x  = fmaf(c0.x, xu.x, acc[0].x);  acc[0].y  = fmaf(c0.x, xu.y, acc[0].y);
      acc[1].x  = fmaf(c0.y, xu.x, acc[1].x);  acc[1].y  = fmaf(c0.y, xu.y, acc[1].y);
      acc[2].x  = fmaf(c0.z, xu.x, acc[2].x);  acc[2].y  = fmaf(c0.z, xu.y, acc[2].y);
      acc[3].x  = fmaf(c0.w, xu.x, acc[3].x);  acc[3].y  = fmaf(c0.w, xu.y, acc[3].y);
      acc[4].x  = fmaf(c1.x, xu.x, acc[4].x);  acc[4].y  = fmaf(c1.x, xu.y, acc[4].y);
      acc[5].x  = fmaf(c1.y, xu.x, acc[5].x);  acc[5].y  = fmaf(c1.y, xu.y, acc[5].y);
      acc[6].x  = fmaf(c1.z, xu.x, acc[6].x);  acc[6].y  = fmaf(c1.z, xu.y, acc[6].y);
      acc[7].x  = fmaf(c1.w, xu.x, acc[7].x);  acc[7].y  = fmaf(c1.w, xu.y, acc[7].y);
      acc[8].x  = fmaf(c2.x, xu.x, acc[8].x);  acc[8].y  = fmaf(c2.x, xu.y, acc[8].y);
      acc[9].x  = fmaf(c2.y, xu.x, acc[9].x);  acc[9].y  = fmaf(c2.y, xu.y, acc[9].y);
      acc[10].x = fmaf(c2.z, xu.x, acc[10].x); acc[10].y = fmaf(c2.z, xu.y, acc[10].y);
      acc[11].x = fmaf(c2.w, xu.x, acc[11].x); acc[11].y = fmaf(c2.w, xu.y, acc[11].y);
      acc[12].x = fmaf(c3.x, xu.x, acc[12].x); acc[12].y = fmaf(c3.x, xu.y, acc[12].y);
      acc[13].x = fmaf(c3.y, xu.x, acc[13].x); acc[13].y = fmaf(c3.y, xu.y, acc[13].y);
      acc[14].x = fmaf(c3.z, xu.x, acc[14].x); acc[14].y = fmaf(c3.z, xu.y, acc[14].y);
      acc[15].x = fmaf(c3.w, xu.x, acc[15].x); acc[15].y = fmaf(c3.w, xu.y, acc[15].y);
    }
  }
  float2* up = (float2*)Upart;
#pragma unroll
  for (int j = 0; j < 16; ++j) {
    int g = slice * 16 + j;
    up[((size_t)blockIdx.y * 64 + g) * 256 + n2] = acc[j];
  }
}

// ---------------- 32x64-tile fp32 GEMM: C[M,N] = A[M,K] @ B[K,N] ----------------
__global__ __launch_bounds__(256) void gemm32x64(const float* __restrict__ A,
                                                 const float* __restrict__ B,
                                                 float* __restrict__ C,
                                                 int M, int N, int K) {
  __shared__ float As[16][33];
  __shared__ float Bs[16][65];
  int tid = threadIdx.x;
  int tx = tid & 15;
  int ty = tid >> 4;
  int bm = blockIdx.x * 32;
  int bn = blockIdx.y * 64;

  int ar = tid >> 3;
  int ac = (tid & 7) * 2;
  int br = tid >> 4;
  int bc = (tid & 15) * 4;

  float acc[2][4] = {};

  for (int k0 = 0; k0 < K; k0 += 16) {
    float2 av = *(const float2*)(A + (size_t)(bm + ar) * K + k0 + ac);
    As[ac + 0][ar] = av.x;
    As[ac + 1][ar] = av.y;
    float4 bv = *(const float4*)(B + (size_t)(k0 + br) * N + bn + bc);
    Bs[br][bc + 0] = bv.x;
    Bs[br][bc + 1] = bv.y;
    Bs[br][bc + 2] = bv.z;
    Bs[br][bc + 3] = bv.w;
    __syncthreads();
#pragma unroll
    for (int kk = 0; kk < 16; ++kk) {
      float a0 = As[kk][ty * 2 + 0];
      float a1 = As[kk][ty * 2 + 1];
      float b0 = Bs[kk][tx * 4 + 0];
      float b1 = Bs[kk][tx * 4 + 1];
      float b2 = Bs[kk][tx * 4 + 2];
      float b3 = Bs[kk][tx * 4 + 3];
      acc[0][0] = fmaf(a0, b0, acc[0][0]); acc[0][1] = fmaf(a0, b1, acc[0][1]);
      acc[0][2] = fmaf(a0, b2, acc[0][2]); acc[0][3] = fmaf(a0, b3, acc[0][3]);
      acc[1][0] = fmaf(a1, b0, acc[1][0]); acc[1][1] = fmaf(a1, b1, acc[1][1]);
      acc[1][2] = fmaf(a1, b2, acc[1][2]); acc[1][3] = fmaf(a1, b3, acc[1][3]);
    }
    __syncthreads();
  }

#pragma unroll
  for (int i = 0; i < 2; ++i) {
    int m = bm + ty * 2 + i;
#pragma unroll
    for (int j = 0; j < 4; ++j) {
      C[(size_t)m * N + bn + tx * 4 + j] = acc[i][j];
    }
  }
}

// ---------------- parallel vec-mat: out[n] = sum_k v[k]*Mat[k][n] ----------------
__global__ __launch_bounds__(512) void vecmat_fast(const float* __restrict__ v,
                                                   const float* __restrict__ Mat,
                                                   float* __restrict__ out, int K, int N) {
  int lane = threadIdx.x & 63;
  int slice = threadIdx.x >> 6;  // 0..7
  int n = blockIdx.x * 64 + lane;
  float acc = 0.f;
  for (int k = slice; k < K; k += 8)
    acc = fmaf(v[k], Mat[(size_t)k * N + n], acc);
  __shared__ float s[8][64];
  s[slice][lane] = acc;
  __syncthreads();
  if (slice == 0) {
    float r = s[0][lane];
#pragma unroll
    for (int q = 1; q < 8; ++q) r += s[q][lane];
    out[n] = r;
  }
}

// ---------------- fused head (reduces Upart inline) ----------------
__global__ __launch_bounds__(256) void head(const float* __restrict__ Upart,
                                            const float* __restrict__ Wc,
                                            const float* __restrict__ v1,
                                            const float* __restrict__ v2,
                                            const float* __restrict__ ng,
                                            const float* __restrict__ eh,
                                            const float* __restrict__ bc1,
                                            const float* __restrict__ Wc2,
                                            const float* __restrict__ bc2,
                                            float* __restrict__ out) {
  int g = blockIdx.x;
  int j = threadIdx.x;
  __shared__ float p[512];
  float s0 = 0.f, s1 = 0.f;
  for (int c = 0; c < NCHUNK; ++c) {
    s0 += Upart[((size_t)c * 64 + g) * DIM + j];
    s1 += Upart[((size_t)c * 64 + g) * DIM + 256 + j];
  }
  p[j] = s0;
  p[j + 256] = s1;
  __syncthreads();
  float cg = ng[g] + eh[g];
  float acc = bc1[j] + cg * v1[j] + ng[g] * v2[j];
  for (int k = 0; k < 512; ++k) acc = fmaf(p[k], Wc[k * 256 + j], acc);
  float z = fmaxf(acc, 0.f);
  float part = z * Wc2[j];
  for (int off = 32; off > 0; off >>= 1) part += __shfl_down(part, off, 64);
  __shared__ float red[4];
  if ((j & 63) == 0) red[j >> 6] = part;
  __syncthreads();
  if (j == 0) {
    float tot = red[0] + red[1] + red[2] + red[3] + bc2[0];
    out[g] = 1.f / (1.f + expf(-tot));
  }
}

extern "C" void kernel_launch(void* const* d_in, const int* in_sizes, int n_in,
                              void* d_out, int out_size, void* d_ws, size_t ws_size,
                              hipStream_t stream) {
  const float* x    = (const float*)d_in[0];
  const int*   ei   = (const int*)d_in[1];
  const int*   batch= (const int*)d_in[2];
  const float* Wg1  = (const float*)d_in[3];
  const float* bg1  = (const float*)d_in[4];
  const float* Wg2  = (const float*)d_in[5];
  const float* bg2  = (const float*)d_in[6];
  const float* Wc1  = (const float*)d_in[7];
  const float* bc1  = (const float*)d_in[8];
  const float* Wc2  = (const float*)d_in[9];
  const float* bc2  = (const float*)d_in[10];
  float* out = (float*)d_out;

  int n_edges = in_sizes[1] / 2;
  int n_nodes = in_sizes[2];
  const int* srcI = ei;
  const int* dstI = ei + n_edges;

  char* ws = (char*)d_ws;
  size_t off = 0;
  auto alloc = [&](size_t bytes) { char* p = ws + off; off += (bytes + 255) & ~(size_t)255; return p; };
  float* wT    = (float*)alloc((size_t)N_NODES * 64 * sizeof(float));        // 5.12 MB
  float* cT    = (float*)alloc((size_t)N_NODES * 64 * sizeof(float));        // 5.12 MB
  float* Upart = (float*)alloc((size_t)NCHUNK * 64 * DIM * sizeof(float));   // 20.6 MB
  float* WC    = (float*)alloc((size_t)DIM * 256 * sizeof(float));           // Wg2@Wc1
  float* Wc    = (float*)alloc((size_t)DIM * 256 * sizeof(float));           // Wg1@WC
  float* v1    = (float*)alloc(256 * sizeof(float));                         // bg1@WC
  float* v2    = (float*)alloc(256 * sizeof(float));                         // bg2@Wc1
  float* ng    = (float*)alloc(NG * sizeof(float));
  float* eh    = (float*)alloc(NG * sizeof(float));
  int* counts  = (int*)alloc(N_NODES * sizeof(int));
  int* rowptr  = (int*)alloc((N_NODES + 1) * sizeof(int));
  int* cursor  = (int*)alloc(N_NODES * sizeof(int));
  int* edst    = (int*)alloc((size_t)n_edges * sizeof(int));

  // --- coefficient build ---
  node_init<<<(n_nodes + 3) / 4, 256, 0, stream>>>(batch, wT, ng, eh, n_nodes);
  edge_pass<<<320, 256, 0, stream>>>(srcI, dstI, batch, wT, eh, n_edges);
  rowsum_counts<<<(n_nodes + 3) / 4, 256, 0, stream>>>(wT, counts, n_nodes);

  // --- CSR by source ---
  scan_counts<<<1, SCAN_THREADS, 0, stream>>>(counts, rowptr, cursor, n_nodes);
  fill_csr<<<320, 256, 0, stream>>>(srcI, dstI, cursor, edst, n_edges);

  // --- c coefficients + U = cT^T @ x (chunked; head reduces partials) ---
  compute_cT<<<(n_nodes + 3) / 4, 256, 0, stream>>>(wT, rowptr, edst, cT, n_nodes);
  ugemm<<<dim3(4, NCHUNK), 256, 0, stream>>>(x, cT, Upart);

  // --- weight precompute: WC = Wg2@Wc1; Wc = Wg1@WC; v1 = bg1@WC; v2 = bg2@Wc1 ---
  gemm32x64<<<dim3(16, 4), 256, 0, stream>>>(Wg2, Wc1, WC, DIM, 256, DIM);
  gemm32x64<<<dim3(16, 4), 256, 0, stream>>>(Wg1, WC, Wc, DIM, 256, DIM);
  vecmat_fast<<<4, 512, 0, stream>>>(bg1, WC, v1, DIM, 256);
  vecmat_fast<<<4, 512, 0, stream>>>(bg2, Wc1, v2, DIM, 256);

  // --- head ---
  head<<<NG, 256, 0, stream>>>(Upart, Wc, v1, v2, ng, eh, bc1, Wc2, bc2, out);
}